// Round 9
// baseline (330.812 us; speedup 1.0000x reference)
//
#include <hip/hip_runtime.h>
#include <hip/hip_bf16.h>
#include <hip/hip_fp16.h>

#define NNODES 50000
#define NEDGES 1600000
#define ETOT   (NNODES + NEDGES)
#define FIN    256
#define HC     128
#define NEG    0.2f
#define DEGCAP 128
#define ALP    (DEGCAP + 8)

// ---------------- shared GEMM body (register-blocked, h stored fp16) ----------------
// XH: input matrix is fp16 (row-major [n][K]); otherwise fp32.
template <int K, bool XH>
__device__ __forceinline__ void gemm_body(
        const void* __restrict__ xv, const float* __restrict__ W,
        const float* __restrict__ a_s, const float* __restrict__ a_d,
        __half* __restrict__ h, float* __restrict__ ls, float* __restrict__ ld_,
        int n, int bid) {
    constexpr int BM = 64, BK = 32;
    __shared__ float xsT[BK][BM];   // element (k,m) at xsT[k][m ^ ((k&7)<<2)]
    __shared__ float ws[BK][HC];
    int t = threadIdx.x;
    int tx = t & 31;
    int ty = t >> 5;
    int r0 = bid * BM;

    float acc[8][4];
#pragma unroll
    for (int r = 0; r < 8; r++)
#pragma unroll
        for (int c = 0; c < 4; c++) acc[r][c] = 0.f;

    for (int kc = 0; kc < K; kc += BK) {
        __syncthreads();
#pragma unroll
        for (int q = 0; q < 2; q++) {
            int idx = q * 256 + t;
            int m = idx >> 3;
            int k4 = (idx & 7) * 4;
            int row = r0 + m;
            float vv[4] = {0.f, 0.f, 0.f, 0.f};
            if (row < n) {
                if constexpr (XH) {
                    const __half* xh = (const __half*)xv;
                    int2 rw = *(const int2*)&xh[(size_t)row * K + kc + k4];
                    float2 f0 = __half22float2(*reinterpret_cast<const __half2*>(&rw.x));
                    float2 f1 = __half22float2(*reinterpret_cast<const __half2*>(&rw.y));
                    vv[0] = f0.x; vv[1] = f0.y; vv[2] = f1.x; vv[3] = f1.y;
                } else {
                    float4 vt = *(const float4*)&((const float*)xv)[(size_t)row * K + kc + k4];
                    vv[0] = vt.x; vv[1] = vt.y; vv[2] = vt.z; vv[3] = vt.w;
                }
            }
#pragma unroll
            for (int j = 0; j < 4; j++) {
                int k = k4 + j;
                xsT[k][m ^ ((k & 7) << 2)] = vv[j];
            }
        }
#pragma unroll
        for (int q = 0; q < 4; q++) {
            int idx = q * 256 + t;
            int k = idx >> 5;
            int n4 = (idx & 31) * 4;
            *(float4*)&ws[k][n4] = *(const float4*)&W[(size_t)(kc + k) * HC + n4];
        }
        __syncthreads();
#pragma unroll
        for (int kk = 0; kk < BK; kk++) {
            int s = (kk & 7) << 2;
            float4 a0 = *(const float4*)&xsT[kk][(8 * ty) ^ s];
            float4 a1 = *(const float4*)&xsT[kk][(8 * ty + 4) ^ s];
            float4 w0 = *(const float4*)&ws[kk][4 * tx];
            float a[8] = {a0.x, a0.y, a0.z, a0.w, a1.x, a1.y, a1.z, a1.w};
            float wv[4] = {w0.x, w0.y, w0.z, w0.w};
#pragma unroll
            for (int r = 0; r < 8; r++)
#pragma unroll
                for (int c = 0; c < 4; c++)
                    acc[r][c] = fmaf(a[r], wv[c], acc[r][c]);
        }
    }

    int head = tx >> 3;
    float4 sa4 = *(const float4*)&a_s[4 * tx];
    float4 sd4 = *(const float4*)&a_d[4 * tx];
    float sa[4] = {sa4.x, sa4.y, sa4.z, sa4.w};
    float sd[4] = {sd4.x, sd4.y, sd4.z, sd4.w};
#pragma unroll
    for (int r = 0; r < 8; r++) {
        int row = r0 + 8 * ty + r;
        if (row >= n) break;
        union { __half2 h2[2]; int2 i2; } u;
        u.h2[0] = __floats2half2_rn(acc[r][0], acc[r][1]);
        u.h2[1] = __floats2half2_rn(acc[r][2], acc[r][3]);
        *(int2*)&h[(size_t)row * HC + 4 * tx] = u.i2;
        float p = acc[r][0] * sa[0] + acc[r][1] * sa[1] + acc[r][2] * sa[2] + acc[r][3] * sa[3];
        float q = acc[r][0] * sd[0] + acc[r][1] * sd[1] + acc[r][2] * sd[2] + acc[r][3] * sd[3];
        p += __shfl_xor(p, 1); q += __shfl_xor(q, 1);
        p += __shfl_xor(p, 2); q += __shfl_xor(q, 2);
        p += __shfl_xor(p, 4); q += __shfl_xor(q, 4);
        if ((tx & 7) == 0) {
            ls[row * 4 + head] = p;
            ld_[row * 4 + head] = q;
        }
    }
}

// ---------------- fused: gemm layer-1 | edge ranking | wedot ----------------
__global__ __launch_bounds__(256) void gemm1_rank_fused(
        const float* __restrict__ x, const float* __restrict__ W,
        const float* __restrict__ a_s, const float* __restrict__ a_d,
        __half* __restrict__ h, float* __restrict__ ls, float* __restrict__ ld_,
        int n,
        const int* __restrict__ ei, unsigned short* __restrict__ rank,
        int* __restrict__ deg, int E,
        const float* We1, const float* ae1, const float* We2, const float* ae2,
        const float* We3, const float* ae3, float* __restrict__ wedot,
        int gB, int rB) {
    int b = blockIdx.x;
    if (b < gB) {
        gemm_body<FIN, false>(x, W, a_s, a_d, h, ls, ld_, n, b);
    } else if (b < gB + rB) {
        int i = (b - gB) * 256 + threadIdx.x;
        if (i < E) rank[i] = (unsigned short)atomicAdd(&deg[ei[E + i]], 1);
    } else {
        int t = threadIdx.x;
        if (t < 128) {
            float p1 = We1[t] * ae1[t];
            float p2 = We2[t] * ae2[t];
            for (int o = 16; o; o >>= 1) {
                p1 += __shfl_xor(p1, o, 32);
                p2 += __shfl_xor(p2, o, 32);
            }
            if ((t & 31) == 0) {
                wedot[t >> 5] = p1;
                wedot[4 + (t >> 5)] = p2;
            }
            if (t == 0) wedot[8] = We3[0] * ae3[0];
        }
    }
}

// standalone gemm (layer 2, fp16 input)
template <int K, bool XH>
__global__ __launch_bounds__(256) void gemm_lsld(
        const void* __restrict__ x, const float* __restrict__ W,
        const float* __restrict__ a_s, const float* __restrict__ a_d,
        __half* __restrict__ h, float* __restrict__ ls, float* __restrict__ ld_,
        int n) {
    gemm_body<K, XH>(x, W, a_s, a_d, h, ls, ld_, n, blockIdx.x);
}

// ---------------- CSR build ----------------

// exclusive scan of (deg[i]+1)  — +1 reserves the self-loop slot per node
__global__ void scan_block(const int* __restrict__ deg, int* __restrict__ out,
                           int* __restrict__ bsum, int n) {
    __shared__ int sh[256];
    int t = threadIdx.x;
    int i = blockIdx.x * 256 + t;
    int v = (i < n) ? (deg[i] + 1) : 0;
    sh[t] = v;
    __syncthreads();
    for (int o = 1; o < 256; o <<= 1) {
        int a = (t >= o) ? sh[t - o] : 0;
        __syncthreads();
        sh[t] += a;
        __syncthreads();
    }
    if (i < n) out[i] = sh[t] - v;
    if (t == 255) bsum[blockIdx.x] = sh[255];
}

__global__ void scan_top(int* __restrict__ bsum, int nb) {
    __shared__ int sh[256];
    int t = threadIdx.x;
    int v = (t < nb) ? bsum[t] : 0;
    sh[t] = v;
    __syncthreads();
    for (int o = 1; o < 256; o <<= 1) {
        int a = (t >= o) ? sh[t - o] : 0;
        __syncthreads();
        sh[t] += a;
        __syncthreads();
    }
    if (t < nb) bsum[t] = sh[t] - v;
}

__global__ void scan_add(int* __restrict__ rp, const int* __restrict__ boff,
                         int n, int etot) {
    int i = blockIdx.x * blockDim.x + threadIdx.x;
    if (i < n)      rp[i] += boff[i >> 8];
    else if (i == n) rp[n] = etot;
}

// atomic-free scatter into packed (src, ea) int2 CSR; last slot per node left unwritten
__global__ void scatter_k(const int* __restrict__ ei, const float* __restrict__ ea,
                          const int* __restrict__ rp, const unsigned short* __restrict__ rank,
                          int2* __restrict__ csr, int E) {
    int i = blockIdx.x * blockDim.x + threadIdx.x;
    if (i < E) {
        int d = ei[E + i];
        int pos = rp[d] + (int)rank[i];
        csr[pos] = make_int2(ei[i], __float_as_int(ea[i]));
    }
}

// ---------------- per-node softmax aggregation (fp16 full-row gather) ----------------
// Self-loop slot (last in segment) is synthesized in-kernel: src=nid, ea=mean(real ea).
template <bool RELU, bool FUSE3>
__global__ __launch_bounds__(128) void agg_k(
        const __half* __restrict__ h, const float* __restrict__ ls,
        const float* __restrict__ ld_, const int* __restrict__ row_ptr,
        const int2* __restrict__ csr,
        const float* __restrict__ wedot, const float* __restrict__ bias,
        __half* __restrict__ out, const float* __restrict__ W3,
        float* __restrict__ h3, int n) {
    __shared__ float albuf[4][ALP];
    __shared__ int srcbuf[DEGCAP];       // pre-scaled row byte offsets (s*256)
    __shared__ float pacc[8][HC];
    __shared__ float redA[2];
    __shared__ float redM[2][4];
    __shared__ float redS[2][4];
    int nid = blockIdx.x;
    int t = threadIdx.x;
    int beg = row_ptr[nid], end = row_ptr[nid + 1];
    int deg = end - beg;                 // includes synthetic self-loop slot

    float v;
    if (deg <= DEGCAP) {
        int degr = deg - 1;              // real edges
        // ---- phase A: one thread per edge slot, all 4 heads at once ----
        int src = nid;
        float eav = 0.f;
        if (t < degr) {
            int2 ce = csr[beg + t];
            src = ce.x;
            eav = __int_as_float(ce.y);
        }
        // block sum of real ea -> self-loop attr
        float es = (t < degr) ? eav : 0.f;
#pragma unroll
        for (int o = 32; o; o >>= 1) es += __shfl_xor(es, o, 64);
        if ((t & 63) == 0) redA[t >> 6] = es;
        __syncthreads();
        es = redA[0] + redA[1];
        if (t == degr) eav = es / fmaxf((float)degr, 1.f);

        float4 wd4 = *(const float4*)wedot;
        float4 ldn4 = *(const float4*)&ld_[nid * 4];
        float lg0, lg1, lg2, lg3;
        if (t < deg) {
            float4 ls4 = *(const float4*)&ls[src * 4];
            lg0 = ls4.x + ldn4.x + eav * wd4.x; lg0 = lg0 > 0.f ? lg0 : NEG * lg0;
            lg1 = ls4.y + ldn4.y + eav * wd4.y; lg1 = lg1 > 0.f ? lg1 : NEG * lg1;
            lg2 = ls4.z + ldn4.z + eav * wd4.z; lg2 = lg2 > 0.f ? lg2 : NEG * lg2;
            lg3 = ls4.w + ldn4.w + eav * wd4.w; lg3 = lg3 > 0.f ? lg3 : NEG * lg3;
            srcbuf[t] = src << 8;        // s * HC * 2 bytes
        } else {
            lg0 = lg1 = lg2 = lg3 = -1e30f;
        }
        // per-head block max
        float m0 = lg0, m1 = lg1, m2 = lg2, m3 = lg3;
#pragma unroll
        for (int o = 32; o; o >>= 1) {
            m0 = fmaxf(m0, __shfl_xor(m0, o, 64));
            m1 = fmaxf(m1, __shfl_xor(m1, o, 64));
            m2 = fmaxf(m2, __shfl_xor(m2, o, 64));
            m3 = fmaxf(m3, __shfl_xor(m3, o, 64));
        }
        if ((t & 63) == 0) {
            redM[t >> 6][0] = m0; redM[t >> 6][1] = m1;
            redM[t >> 6][2] = m2; redM[t >> 6][3] = m3;
        }
        __syncthreads();
        m0 = fmaxf(redM[0][0], redM[1][0]);
        m1 = fmaxf(redM[0][1], redM[1][1]);
        m2 = fmaxf(redM[0][2], redM[1][2]);
        m3 = fmaxf(redM[0][3], redM[1][3]);
        // exp -> albuf, per-head block sum
        float s0 = 0.f, s1 = 0.f, s2 = 0.f, s3 = 0.f;
        if (t < deg) {
            s0 = __expf(lg0 - m0); albuf[0][t] = s0;
            s1 = __expf(lg1 - m1); albuf[1][t] = s1;
            s2 = __expf(lg2 - m2); albuf[2][t] = s2;
            s3 = __expf(lg3 - m3); albuf[3][t] = s3;
        }
#pragma unroll
        for (int o = 32; o; o >>= 1) {
            s0 += __shfl_xor(s0, o, 64);
            s1 += __shfl_xor(s1, o, 64);
            s2 += __shfl_xor(s2, o, 64);
            s3 += __shfl_xor(s3, o, 64);
        }
        if ((t & 63) == 0) {
            redS[t >> 6][0] = s0; redS[t >> 6][1] = s1;
            redS[t >> 6][2] = s2; redS[t >> 6][3] = s3;
        }
        __syncthreads();                 // also publishes albuf/srcbuf
        s0 = redS[0][0] + redS[1][0];
        s1 = redS[0][1] + redS[1][1];
        s2 = redS[0][2] + redS[1][2];
        s3 = redS[0][3] + redS[1][3];

        // ---- phase C: 8 groups x 16 lanes; group g -> edges g, g+8, ... ----
        int g = t >> 4, l = t & 15;
        int c0 = 8 * l;
        const float* al = albuf[c0 >> 5];
        const char* hb = (const char*)h + 16 * l;
        float acc[8];
#pragma unroll
        for (int j = 0; j < 8; j++) acc[j] = 0.f;
        int e = g;
        for (; e + 8 < deg; e += 16) {
            int o0 = srcbuf[e], o1 = srcbuf[e + 8];
            int4 r0 = *(const int4*)(hb + o0);
            int4 r1 = *(const int4*)(hb + o1);
            float a0 = al[e], a1 = al[e + 8];
            const __half2* p0 = (const __half2*)&r0;
            const __half2* p1 = (const __half2*)&r1;
#pragma unroll
            for (int j = 0; j < 4; j++) {
                float2 f0 = __half22float2(p0[j]);
                float2 f1 = __half22float2(p1[j]);
                acc[2 * j]     = fmaf(a0, f0.x, acc[2 * j]);
                acc[2 * j + 1] = fmaf(a0, f0.y, acc[2 * j + 1]);
                acc[2 * j]     = fmaf(a1, f1.x, acc[2 * j]);
                acc[2 * j + 1] = fmaf(a1, f1.y, acc[2 * j + 1]);
            }
        }
        for (; e < deg; e += 8) {
            int o0 = srcbuf[e];
            int4 r0 = *(const int4*)(hb + o0);
            float a0 = al[e];
            const __half2* p0 = (const __half2*)&r0;
#pragma unroll
            for (int j = 0; j < 4; j++) {
                float2 f0 = __half22float2(p0[j]);
                acc[2 * j]     = fmaf(a0, f0.x, acc[2 * j]);
                acc[2 * j + 1] = fmaf(a0, f0.y, acc[2 * j + 1]);
            }
        }
#pragma unroll
        for (int j = 0; j < 4; j++)
            *(float2*)&pacc[g][c0 + 2 * j] = make_float2(acc[2 * j], acc[2 * j + 1]);
        __syncthreads();

        int head = t >> 5;
        float sumh = (head == 0) ? s0 : (head == 1) ? s1 : (head == 2) ? s2 : s3;
        float inv = 1.f / (sumh + 1e-16f);
        float sv = pacc[0][t];
#pragma unroll
        for (int g2 = 1; g2 < 8; g2++) sv += pacc[g2][t];
        v = sv * inv + bias[t];
    } else {
        // fallback (deg > DEGCAP): recompute path with synthesized self-loop
        int head = t >> 5, lane = t & 31;
        float ldn = ld_[nid * 4 + head];
        float wd = wedot[head];
        int endr = end - 1;
        float easum = 0.f, mx = -1e30f;
        for (int j = beg + lane; j < endr; j += 32) {
            int2 ce = csr[j];
            float eav = __int_as_float(ce.y);
            easum += eav;
            float lg = ls[ce.x * 4 + head] + ldn + eav * wd;
            lg = lg > 0.f ? lg : NEG * lg;
            mx = fmaxf(mx, lg);
        }
        for (int o = 16; o; o >>= 1) {
            easum += __shfl_xor(easum, o, 32);
            mx = fmaxf(mx, __shfl_xor(mx, o, 32));
        }
        float mean = easum / fmaxf((float)(endr - beg), 1.f);
        float lgs = ls[nid * 4 + head] + ldn + mean * wd;
        lgs = lgs > 0.f ? lgs : NEG * lgs;
        mx = fmaxf(mx, lgs);
        float sum = __expf(lgs - mx);
        float acc = sum * __half2float(h[(size_t)nid * HC + t]);
        for (int j = beg; j < endr; j++) {
            int2 ce = csr[j];
            float lg = ls[ce.x * 4 + head] + ldn + __int_as_float(ce.y) * wd;
            lg = lg > 0.f ? lg : NEG * lg;
            float p = __expf(lg - mx);
            sum += p;
            acc = fmaf(p, __half2float(h[(size_t)ce.x * HC + t]), acc);
        }
        v = acc / (sum + 1e-16f) + bias[t];
    }

    if (RELU) v = fmaxf(v, 0.f);
    if (!FUSE3) out[(size_t)nid * HC + t] = __float2half(v);

    if (FUSE3) {
        float p = v * W3[t];
        for (int o = 32; o; o >>= 1) p += __shfl_xor(p, o, 64);
        __shared__ float sh[2];
        if ((t & 63) == 0) sh[t >> 6] = p;
        __syncthreads();
        if (t == 0) h3[nid] = sh[0] + sh[1];
    }
}

// ---------------- layer 3 (1 head, 1 channel), 8 lanes per node, synth self-loop ----------------
__global__ __launch_bounds__(256) void layer3_k(
        const float* __restrict__ h3, const int* __restrict__ row_ptr,
        const int2* __restrict__ csr,
        const float* __restrict__ wedot, const float* __restrict__ as3,
        const float* __restrict__ ad3, const float* __restrict__ b3,
        float* __restrict__ out, int n) {
    int idx = blockIdx.x * blockDim.x + threadIdx.x;
    int node = idx >> 3, l = idx & 7;
    if (node >= n) return;
    float A = as3[0], D = ad3[0], wd = wedot[8];
    int beg = row_ptr[node], endr = row_ptr[node + 1] - 1;
    float hs = h3[node];
    float hdn = hs * D;

    float easum = 0.f, mx = -1e30f;
    for (int j = beg + l; j < endr; j += 8) {
        int2 ce = csr[j];
        float eav = __int_as_float(ce.y);
        easum += eav;
        float lg = h3[ce.x] * A + hdn + eav * wd;
        lg = lg > 0.f ? lg : NEG * lg;
        mx = fmaxf(mx, lg);
    }
    easum += __shfl_xor(easum, 1, 8); mx = fmaxf(mx, __shfl_xor(mx, 1, 8));
    easum += __shfl_xor(easum, 2, 8); mx = fmaxf(mx, __shfl_xor(mx, 2, 8));
    easum += __shfl_xor(easum, 4, 8); mx = fmaxf(mx, __shfl_xor(mx, 4, 8));
    float mean = easum / fmaxf((float)(endr - beg), 1.f);
    float lgs = hs * A + hdn + mean * wd;
    lgs = lgs > 0.f ? lgs : NEG * lgs;
    mx = fmaxf(mx, lgs);

    float sum = 0.f, num = 0.f;
    for (int j = beg + l; j < endr; j += 8) {
        int2 ce = csr[j];
        float hv = h3[ce.x];
        float lg = hv * A + hdn + __int_as_float(ce.y) * wd;
        lg = lg > 0.f ? lg : NEG * lg;
        float p = __expf(lg - mx);
        sum += p;
        num = fmaf(p, hv, num);
    }
    sum += __shfl_xor(sum, 1, 8); num += __shfl_xor(num, 1, 8);
    sum += __shfl_xor(sum, 2, 8); num += __shfl_xor(num, 2, 8);
    sum += __shfl_xor(sum, 4, 8); num += __shfl_xor(num, 4, 8);
    if (l == 0) {
        float p = __expf(lgs - mx);
        sum += p;
        num = fmaf(p, hs, num);
        out[node] = num / (sum + 1e-16f) + b3[0];
    }
}

// ---------------- launch ----------------

extern "C" void kernel_launch(void* const* d_in, const int* in_sizes, int n_in,
                              void* d_out, int out_size, void* d_ws, size_t ws_size,
                              hipStream_t stream) {
    const float* x   = (const float*)d_in[0];
    const int*   ei  = (const int*)d_in[1];
    const float* ea  = (const float*)d_in[2];
    const float* W1  = (const float*)d_in[3];
    const float* We1 = (const float*)d_in[4];
    const float* as1 = (const float*)d_in[5];
    const float* ad1 = (const float*)d_in[6];
    const float* ae1 = (const float*)d_in[7];
    const float* b1  = (const float*)d_in[8];
    const float* W2  = (const float*)d_in[9];
    const float* We2 = (const float*)d_in[10];
    const float* as2 = (const float*)d_in[11];
    const float* ad2 = (const float*)d_in[12];
    const float* ae2 = (const float*)d_in[13];
    const float* b2  = (const float*)d_in[14];
    const float* W3  = (const float*)d_in[15];
    const float* We3 = (const float*)d_in[16];
    const float* as3 = (const float*)d_in[17];
    const float* ad3 = (const float*)d_in[18];
    const float* ae3 = (const float*)d_in[19];
    const float* b3  = (const float*)d_in[20];

    const int N = NNODES, E = NEDGES, etot = ETOT;

    char* ws = (char*)d_ws;
    size_t o = 0;
    auto alloc = [&](size_t bytes) { size_t r = o; o = (o + bytes + 255) & ~(size_t)255; return r; };
    size_t o_deg   = alloc((size_t)N * 4);
    size_t zero_span = o;
    size_t o_rp    = alloc((size_t)(N + 1) * 4);
    size_t o_bsum  = alloc(256 * 4);
    size_t o_wd    = alloc(16 * 4);
    size_t o_rank  = alloc((size_t)E * 2);        // u16 ranks
    size_t o_csr   = alloc((size_t)etot * 8);
    size_t o_ls    = alloc((size_t)N * 4 * 4);
    size_t o_ld    = alloc((size_t)N * 4 * 4);
    size_t o_h3    = alloc((size_t)N * 4);
    size_t o_h16   = alloc((size_t)N * HC * 2);   // fp16 feature rows (layer 1 then layer 2)
    size_t o_h16b  = alloc((size_t)N * HC * 2);   // fp16 agg-1 output

    int*            deg   = (int*)(ws + o_deg);
    int*            rp    = (int*)(ws + o_rp);
    int*            bsum  = (int*)(ws + o_bsum);
    float*          wd    = (float*)(ws + o_wd);
    unsigned short* rank  = (unsigned short*)(ws + o_rank);
    int2*           csr   = (int2*)(ws + o_csr);
    float*          ls    = (float*)(ws + o_ls);
    float*          ld_   = (float*)(ws + o_ld);
    float*          h3    = (float*)(ws + o_h3);
    __half*         h16   = (__half*)(ws + o_h16);
    __half*         h16b  = (__half*)(ws + o_h16b);

    hipMemsetAsync(ws, 0, zero_span, stream);

    int gB = (N + 63) / 64;          // 782 gemm tiles
    int rB = (E + 255) / 256;        // 6250 rank chunks
    int nb = (N + 255) / 256;

    // fused: gemm layer-1 || edge ranking || wedot
    gemm1_rank_fused<<<gB + rB + 1, 256, 0, stream>>>(
        x, W1, as1, ad1, h16, ls, ld_, N,
        ei, rank, deg, E,
        We1, ae1, We2, ae2, We3, ae3, wd, gB, rB);

    scan_block<<<nb, 256, 0, stream>>>(deg, rp, bsum, N);
    scan_top<<<1, 256, 0, stream>>>(bsum, nb);
    scan_add<<<(N + 256) / 256, 256, 0, stream>>>(rp, bsum, N, etot);
    scatter_k<<<(E + 255) / 256, 256, 0, stream>>>(ei, ea, rp, rank, csr, E);

    // layer 1 aggregation (writes fp16)
    agg_k<true, false><<<N, 128, 0, stream>>>(h16, ls, ld_, rp, csr, wd, b1,
                                              h16b, nullptr, nullptr, N);
    // layer 2 (+ fused layer-3 projection)
    gemm_lsld<HC, true><<<(N + 63) / 64, 256, 0, stream>>>(h16b, W2, as2, ad2,
                                                           h16, ls, ld_, N);
    agg_k<true, true><<<N, 128, 0, stream>>>(h16, ls, ld_, rp, csr, wd + 4, b2,
                                             nullptr, W3, h3, N);
    // layer 3
    layer3_k<<<(N * 8 + 255) / 256, 256, 0, stream>>>(h3, rp, csr, wd, as3, ad3, b3,
                                                      (float*)d_out, N);
}

// Round 10
// 301.873 us; speedup vs baseline: 1.0959x; 1.0959x over previous
//
#include <hip/hip_runtime.h>
#include <hip/hip_bf16.h>
#include <hip/hip_fp16.h>

#define NNODES 50000
#define NEDGES 1600000
#define ETOT   (NNODES + NEDGES)
#define FIN    256
#define HC     128
#define NEG    0.2f
#define DEGCAP 128
#define ALP    (DEGCAP + 8)

// ---------------- shared GEMM body (register-blocked, h stored fp16) ----------------
// XH: input matrix is fp16 (row-major [n][K]); otherwise fp32.
template <int K, bool XH>
__device__ __forceinline__ void gemm_body(
        const void* __restrict__ xv, const float* __restrict__ W,
        const float* __restrict__ a_s, const float* __restrict__ a_d,
        __half* __restrict__ h, float* __restrict__ ls, float* __restrict__ ld_,
        int n, int bid) {
    constexpr int BM = 64, BK = 32;
    __shared__ float xsT[BK][BM];   // element (k,m) at xsT[k][m ^ ((k&7)<<2)]
    __shared__ float ws[BK][HC];
    int t = threadIdx.x;
    int tx = t & 31;
    int ty = t >> 5;
    int r0 = bid * BM;

    float acc[8][4];
#pragma unroll
    for (int r = 0; r < 8; r++)
#pragma unroll
        for (int c = 0; c < 4; c++) acc[r][c] = 0.f;

    for (int kc = 0; kc < K; kc += BK) {
        __syncthreads();
#pragma unroll
        for (int q = 0; q < 2; q++) {
            int idx = q * 256 + t;
            int m = idx >> 3;
            int k4 = (idx & 7) * 4;
            int row = r0 + m;
            float vv[4] = {0.f, 0.f, 0.f, 0.f};
            if (row < n) {
                if constexpr (XH) {
                    const __half* xh = (const __half*)xv;
                    int2 rw = *(const int2*)&xh[(size_t)row * K + kc + k4];
                    float2 f0 = __half22float2(*reinterpret_cast<const __half2*>(&rw.x));
                    float2 f1 = __half22float2(*reinterpret_cast<const __half2*>(&rw.y));
                    vv[0] = f0.x; vv[1] = f0.y; vv[2] = f1.x; vv[3] = f1.y;
                } else {
                    float4 vt = *(const float4*)&((const float*)xv)[(size_t)row * K + kc + k4];
                    vv[0] = vt.x; vv[1] = vt.y; vv[2] = vt.z; vv[3] = vt.w;
                }
            }
#pragma unroll
            for (int j = 0; j < 4; j++) {
                int k = k4 + j;
                xsT[k][m ^ ((k & 7) << 2)] = vv[j];
            }
        }
#pragma unroll
        for (int q = 0; q < 4; q++) {
            int idx = q * 256 + t;
            int k = idx >> 5;
            int n4 = (idx & 31) * 4;
            *(float4*)&ws[k][n4] = *(const float4*)&W[(size_t)(kc + k) * HC + n4];
        }
        __syncthreads();
#pragma unroll
        for (int kk = 0; kk < BK; kk++) {
            int s = (kk & 7) << 2;
            float4 a0 = *(const float4*)&xsT[kk][(8 * ty) ^ s];
            float4 a1 = *(const float4*)&xsT[kk][(8 * ty + 4) ^ s];
            float4 w0 = *(const float4*)&ws[kk][4 * tx];
            float a[8] = {a0.x, a0.y, a0.z, a0.w, a1.x, a1.y, a1.z, a1.w};
            float wv[4] = {w0.x, w0.y, w0.z, w0.w};
#pragma unroll
            for (int r = 0; r < 8; r++)
#pragma unroll
                for (int c = 0; c < 4; c++)
                    acc[r][c] = fmaf(a[r], wv[c], acc[r][c]);
        }
    }

    int head = tx >> 3;
    float4 sa4 = *(const float4*)&a_s[4 * tx];
    float4 sd4 = *(const float4*)&a_d[4 * tx];
    float sa[4] = {sa4.x, sa4.y, sa4.z, sa4.w};
    float sd[4] = {sd4.x, sd4.y, sd4.z, sd4.w};
#pragma unroll
    for (int r = 0; r < 8; r++) {
        int row = r0 + 8 * ty + r;
        if (row >= n) break;
        union { __half2 h2[2]; int2 i2; } u;
        u.h2[0] = __floats2half2_rn(acc[r][0], acc[r][1]);
        u.h2[1] = __floats2half2_rn(acc[r][2], acc[r][3]);
        *(int2*)&h[(size_t)row * HC + 4 * tx] = u.i2;
        float p = acc[r][0] * sa[0] + acc[r][1] * sa[1] + acc[r][2] * sa[2] + acc[r][3] * sa[3];
        float q = acc[r][0] * sd[0] + acc[r][1] * sd[1] + acc[r][2] * sd[2] + acc[r][3] * sd[3];
        p += __shfl_xor(p, 1); q += __shfl_xor(q, 1);
        p += __shfl_xor(p, 2); q += __shfl_xor(q, 2);
        p += __shfl_xor(p, 4); q += __shfl_xor(q, 4);
        if ((tx & 7) == 0) {
            ls[row * 4 + head] = p;
            ld_[row * 4 + head] = q;
        }
    }
}

// ---------------- fused: gemm layer-1 | edge ranking | wedot ----------------
__global__ __launch_bounds__(256) void gemm1_rank_fused(
        const float* __restrict__ x, const float* __restrict__ W,
        const float* __restrict__ a_s, const float* __restrict__ a_d,
        __half* __restrict__ h, float* __restrict__ ls, float* __restrict__ ld_,
        int n,
        const int* __restrict__ ei, unsigned short* __restrict__ rank,
        int* __restrict__ deg, int E,
        const float* We1, const float* ae1, const float* We2, const float* ae2,
        const float* We3, const float* ae3, float* __restrict__ wedot,
        int gB, int rB) {
    int b = blockIdx.x;
    if (b < gB) {
        gemm_body<FIN, false>(x, W, a_s, a_d, h, ls, ld_, n, b);
    } else if (b < gB + rB) {
        int i = (b - gB) * 256 + threadIdx.x;
        if (i < E) rank[i] = (unsigned short)atomicAdd(&deg[ei[E + i]], 1);
    } else {
        int t = threadIdx.x;
        if (t < 128) {
            float p1 = We1[t] * ae1[t];
            float p2 = We2[t] * ae2[t];
            for (int o = 16; o; o >>= 1) {
                p1 += __shfl_xor(p1, o, 32);
                p2 += __shfl_xor(p2, o, 32);
            }
            if ((t & 31) == 0) {
                wedot[t >> 5] = p1;
                wedot[4 + (t >> 5)] = p2;
            }
            if (t == 0) wedot[8] = We3[0] * ae3[0];
        }
    }
}

// standalone gemm (layer 2, fp16 input)
template <int K, bool XH>
__global__ __launch_bounds__(256) void gemm_lsld(
        const void* __restrict__ x, const float* __restrict__ W,
        const float* __restrict__ a_s, const float* __restrict__ a_d,
        __half* __restrict__ h, float* __restrict__ ls, float* __restrict__ ld_,
        int n) {
    gemm_body<K, XH>(x, W, a_s, a_d, h, ls, ld_, n, blockIdx.x);
}

// ---------------- CSR build ----------------

// exclusive scan of (deg[i]+1)  — +1 reserves the self-loop slot per node
__global__ void scan_block(const int* __restrict__ deg, int* __restrict__ out,
                           int* __restrict__ bsum, int n) {
    __shared__ int sh[256];
    int t = threadIdx.x;
    int i = blockIdx.x * 256 + t;
    int v = (i < n) ? (deg[i] + 1) : 0;
    sh[t] = v;
    __syncthreads();
    for (int o = 1; o < 256; o <<= 1) {
        int a = (t >= o) ? sh[t - o] : 0;
        __syncthreads();
        sh[t] += a;
        __syncthreads();
    }
    if (i < n) out[i] = sh[t] - v;
    if (t == 255) bsum[blockIdx.x] = sh[255];
}

__global__ void scan_top(int* __restrict__ bsum, int nb) {
    __shared__ int sh[256];
    int t = threadIdx.x;
    int v = (t < nb) ? bsum[t] : 0;
    sh[t] = v;
    __syncthreads();
    for (int o = 1; o < 256; o <<= 1) {
        int a = (t >= o) ? sh[t - o] : 0;
        __syncthreads();
        sh[t] += a;
        __syncthreads();
    }
    if (t < nb) bsum[t] = sh[t] - v;
}

__global__ void scan_add(int* __restrict__ rp, const int* __restrict__ boff,
                         int n, int etot) {
    int i = blockIdx.x * blockDim.x + threadIdx.x;
    if (i < n)      rp[i] += boff[i >> 8];
    else if (i == n) rp[n] = etot;
}

// atomic-free scatter into packed (src, ea) int2 CSR; last slot per node left unwritten
__global__ void scatter_k(const int* __restrict__ ei, const float* __restrict__ ea,
                          const int* __restrict__ rp, const unsigned short* __restrict__ rank,
                          int2* __restrict__ csr, int E) {
    int i = blockIdx.x * blockDim.x + threadIdx.x;
    if (i < E) {
        int d = ei[E + i];
        int pos = rp[d] + (int)rank[i];
        csr[pos] = make_int2(ei[i], __float_as_int(ea[i]));
    }
}

// ---------------- per-node softmax aggregation (fp16 full-row gather) ----------------
// Self-loop slot (last in segment) synthesized in-wave: src=nid, ea=mean(real ea).
template <bool RELU, bool FUSE3>
__global__ __launch_bounds__(128) void agg_k(
        const __half* __restrict__ h, const float* __restrict__ ls,
        const float* __restrict__ ld_, const int* __restrict__ row_ptr,
        const int2* __restrict__ csr,
        const float* __restrict__ wedot, const float* __restrict__ bias,
        __half* __restrict__ out, const float* __restrict__ W3,
        float* __restrict__ h3, int n) {
    __shared__ float albuf[4][ALP];
    __shared__ int srcbuf[DEGCAP];       // pre-scaled row byte offsets (s*256)
    __shared__ float pacc[8][HC];
    __shared__ float hsuminv[4];
    int nid = blockIdx.x;
    int t = threadIdx.x, head = t >> 5, lane = t & 31;
    int beg = row_ptr[nid], end = row_ptr[nid + 1];
    int deg = end - beg;                 // includes synthetic self-loop slot
    float ldn = ld_[nid * 4 + head];
    float wd = wedot[head];

    float v;
    if (deg <= DEGCAP) {
        int degr = deg - 1;              // real edges
        // phase A: per-head-wave, logits in static registers; easum for self-loop
        float lgr[4];
        float mx = -1e30f, easum = 0.f;
#pragma unroll
        for (int i = 0; i < 4; i++) {
            int e = lane + 32 * i;
            float lg = -1e30f;
            if (e < degr) {
                int2 ce = csr[beg + e];
                if (head == 0) srcbuf[e] = ce.x << 8;   // s * HC * 2 bytes
                float eav = __int_as_float(ce.y);
                easum += eav;
                lg = ls[ce.x * 4 + head] + ldn + eav * wd;
                lg = lg > 0.f ? lg : NEG * lg;
            }
            lgr[i] = lg;
            mx = fmaxf(mx, lg);
        }
        for (int o = 16; o; o >>= 1) {
            easum += __shfl_xor(easum, o, 32);
            mx = fmaxf(mx, __shfl_xor(mx, o, 32));
        }
        // self-loop logit (computed redundantly on all lanes of the wave)
        float mean = easum / fmaxf((float)degr, 1.f);
        float lgs = ls[nid * 4 + head] + ldn + mean * wd;
        lgs = lgs > 0.f ? lgs : NEG * lgs;
        mx = fmaxf(mx, lgs);

        // phase B: exp -> albuf, per-head sum; lane 0 appends self-loop
        float sum = 0.f;
#pragma unroll
        for (int i = 0; i < 4; i++) {
            int e = lane + 32 * i;
            if (e < degr) {
                float p = __expf(lgr[i] - mx);
                albuf[head][e] = p;
                sum += p;
            }
        }
        for (int o = 16; o; o >>= 1) sum += __shfl_xor(sum, o, 32);
        if (lane == 0) {
            float ps = __expf(lgs - mx);
            albuf[head][degr] = ps;
            hsuminv[head] = 1.f / (sum + ps + 1e-16f);
            if (head == 0) srcbuf[degr] = nid << 8;
        }
        __syncthreads();

        // phase C: 8 groups x 16 lanes; group g -> edges g, g+8, ...
        int g = t >> 4, l = t & 15;
        int c0 = 8 * l;
        const float* al = albuf[c0 >> 5];
        const char* hb = (const char*)h + 16 * l;
        float acc[8];
#pragma unroll
        for (int j = 0; j < 8; j++) acc[j] = 0.f;
        int e = g;
        for (; e + 8 < deg; e += 16) {
            int o0 = srcbuf[e], o1 = srcbuf[e + 8];
            int4 r0 = *(const int4*)(hb + o0);
            int4 r1 = *(const int4*)(hb + o1);
            float a0 = al[e], a1 = al[e + 8];
            const __half2* p0 = (const __half2*)&r0;
            const __half2* p1 = (const __half2*)&r1;
#pragma unroll
            for (int j = 0; j < 4; j++) {
                float2 f0 = __half22float2(p0[j]);
                float2 f1 = __half22float2(p1[j]);
                acc[2 * j]     = fmaf(a0, f0.x, acc[2 * j]);
                acc[2 * j + 1] = fmaf(a0, f0.y, acc[2 * j + 1]);
                acc[2 * j]     = fmaf(a1, f1.x, acc[2 * j]);
                acc[2 * j + 1] = fmaf(a1, f1.y, acc[2 * j + 1]);
            }
        }
        for (; e < deg; e += 8) {
            int o0 = srcbuf[e];
            int4 r0 = *(const int4*)(hb + o0);
            float a0 = al[e];
            const __half2* p0 = (const __half2*)&r0;
#pragma unroll
            for (int j = 0; j < 4; j++) {
                float2 f0 = __half22float2(p0[j]);
                acc[2 * j]     = fmaf(a0, f0.x, acc[2 * j]);
                acc[2 * j + 1] = fmaf(a0, f0.y, acc[2 * j + 1]);
            }
        }
#pragma unroll
        for (int j = 0; j < 4; j++)
            *(float2*)&pacc[g][c0 + 2 * j] = make_float2(acc[2 * j], acc[2 * j + 1]);
        __syncthreads();

        float inv = hsuminv[head];
        float sv = pacc[0][t];
#pragma unroll
        for (int g2 = 1; g2 < 8; g2++) sv += pacc[g2][t];
        v = sv * inv + bias[t];
    } else {
        // fallback (deg > DEGCAP): recompute path with synthesized self-loop
        int endr = end - 1;
        float easum = 0.f, mx = -1e30f;
        for (int j = beg + lane; j < endr; j += 32) {
            int2 ce = csr[j];
            float eav = __int_as_float(ce.y);
            easum += eav;
            float lg = ls[ce.x * 4 + head] + ldn + eav * wd;
            lg = lg > 0.f ? lg : NEG * lg;
            mx = fmaxf(mx, lg);
        }
        for (int o = 16; o; o >>= 1) {
            easum += __shfl_xor(easum, o, 32);
            mx = fmaxf(mx, __shfl_xor(mx, o, 32));
        }
        float mean = easum / fmaxf((float)(endr - beg), 1.f);
        float lgs = ls[nid * 4 + head] + ldn + mean * wd;
        lgs = lgs > 0.f ? lgs : NEG * lgs;
        mx = fmaxf(mx, lgs);
        float sum = __expf(lgs - mx);
        float acc = sum * __half2float(h[(size_t)nid * HC + t]);
        for (int j = beg; j < endr; j++) {
            int2 ce = csr[j];
            float lg = ls[ce.x * 4 + head] + ldn + __int_as_float(ce.y) * wd;
            lg = lg > 0.f ? lg : NEG * lg;
            float p = __expf(lg - mx);
            sum += p;
            acc = fmaf(p, __half2float(h[(size_t)ce.x * HC + t]), acc);
        }
        v = acc / (sum + 1e-16f) + bias[t];
        __syncthreads();
        __syncthreads();   // match fast path's barrier count (uniform per block anyway)
    }

    if (RELU) v = fmaxf(v, 0.f);
    if (!FUSE3) out[(size_t)nid * HC + t] = __float2half(v);

    if (FUSE3) {
        float p = v * W3[t];
        for (int o = 32; o; o >>= 1) p += __shfl_xor(p, o, 64);
        __shared__ float sh[2];
        if ((t & 63) == 0) sh[t >> 6] = p;
        __syncthreads();
        if (t == 0) h3[nid] = sh[0] + sh[1];
    }
}

// ---------------- layer 3 (1 head, 1 channel), 8 lanes per node, synth self-loop ----------------
__global__ __launch_bounds__(256) void layer3_k(
        const float* __restrict__ h3, const int* __restrict__ row_ptr,
        const int2* __restrict__ csr,
        const float* __restrict__ wedot, const float* __restrict__ as3,
        const float* __restrict__ ad3, const float* __restrict__ b3,
        float* __restrict__ out, int n) {
    int idx = blockIdx.x * blockDim.x + threadIdx.x;
    int node = idx >> 3, l = idx & 7;
    if (node >= n) return;
    float A = as3[0], D = ad3[0], wd = wedot[8];
    int beg = row_ptr[node], endr = row_ptr[node + 1] - 1;
    float hs = h3[node];
    float hdn = hs * D;

    float easum = 0.f, mx = -1e30f;
    for (int j = beg + l; j < endr; j += 8) {
        int2 ce = csr[j];
        float eav = __int_as_float(ce.y);
        easum += eav;
        float lg = h3[ce.x] * A + hdn + eav * wd;
        lg = lg > 0.f ? lg : NEG * lg;
        mx = fmaxf(mx, lg);
    }
    easum += __shfl_xor(easum, 1, 8); mx = fmaxf(mx, __shfl_xor(mx, 1, 8));
    easum += __shfl_xor(easum, 2, 8); mx = fmaxf(mx, __shfl_xor(mx, 2, 8));
    easum += __shfl_xor(easum, 4, 8); mx = fmaxf(mx, __shfl_xor(mx, 4, 8));
    float mean = easum / fmaxf((float)(endr - beg), 1.f);
    float lgs = hs * A + hdn + mean * wd;
    lgs = lgs > 0.f ? lgs : NEG * lgs;
    mx = fmaxf(mx, lgs);

    float sum = 0.f, num = 0.f;
    for (int j = beg + l; j < endr; j += 8) {
        int2 ce = csr[j];
        float hv = h3[ce.x];
        float lg = hv * A + hdn + __int_as_float(ce.y) * wd;
        lg = lg > 0.f ? lg : NEG * lg;
        float p = __expf(lg - mx);
        sum += p;
        num = fmaf(p, hv, num);
    }
    sum += __shfl_xor(sum, 1, 8); num += __shfl_xor(num, 1, 8);
    sum += __shfl_xor(sum, 2, 8); num += __shfl_xor(num, 2, 8);
    sum += __shfl_xor(sum, 4, 8); num += __shfl_xor(num, 4, 8);
    if (l == 0) {
        float p = __expf(lgs - mx);
        sum += p;
        num = fmaf(p, hs, num);
        out[node] = num / (sum + 1e-16f) + b3[0];
    }
}

// ---------------- launch ----------------

extern "C" void kernel_launch(void* const* d_in, const int* in_sizes, int n_in,
                              void* d_out, int out_size, void* d_ws, size_t ws_size,
                              hipStream_t stream) {
    const float* x   = (const float*)d_in[0];
    const int*   ei  = (const int*)d_in[1];
    const float* ea  = (const float*)d_in[2];
    const float* W1  = (const float*)d_in[3];
    const float* We1 = (const float*)d_in[4];
    const float* as1 = (const float*)d_in[5];
    const float* ad1 = (const float*)d_in[6];
    const float* ae1 = (const float*)d_in[7];
    const float* b1  = (const float*)d_in[8];
    const float* W2  = (const float*)d_in[9];
    const float* We2 = (const float*)d_in[10];
    const float* as2 = (const float*)d_in[11];
    const float* ad2 = (const float*)d_in[12];
    const float* ae2 = (const float*)d_in[13];
    const float* b2  = (const float*)d_in[14];
    const float* W3  = (const float*)d_in[15];
    const float* We3 = (const float*)d_in[16];
    const float* as3 = (const float*)d_in[17];
    const float* ad3 = (const float*)d_in[18];
    const float* ae3 = (const float*)d_in[19];
    const float* b3  = (const float*)d_in[20];

    const int N = NNODES, E = NEDGES, etot = ETOT;

    char* ws = (char*)d_ws;
    size_t o = 0;
    auto alloc = [&](size_t bytes) { size_t r = o; o = (o + bytes + 255) & ~(size_t)255; return r; };
    size_t o_deg   = alloc((size_t)N * 4);
    size_t zero_span = o;
    size_t o_rp    = alloc((size_t)(N + 1) * 4);
    size_t o_bsum  = alloc(256 * 4);
    size_t o_wd    = alloc(16 * 4);
    size_t o_rank  = alloc((size_t)E * 2);        // u16 ranks
    size_t o_csr   = alloc((size_t)etot * 8);
    size_t o_ls    = alloc((size_t)N * 4 * 4);
    size_t o_ld    = alloc((size_t)N * 4 * 4);
    size_t o_h3    = alloc((size_t)N * 4);
    size_t o_h16   = alloc((size_t)N * HC * 2);   // fp16 feature rows (layer 1 then layer 2)
    size_t o_h16b  = alloc((size_t)N * HC * 2);   // fp16 agg-1 output

    int*            deg   = (int*)(ws + o_deg);
    int*            rp    = (int*)(ws + o_rp);
    int*            bsum  = (int*)(ws + o_bsum);
    float*          wd    = (float*)(ws + o_wd);
    unsigned short* rank  = (unsigned short*)(ws + o_rank);
    int2*           csr   = (int2*)(ws + o_csr);
    float*          ls    = (float*)(ws + o_ls);
    float*          ld_   = (float*)(ws + o_ld);
    float*          h3    = (float*)(ws + o_h3);
    __half*         h16   = (__half*)(ws + o_h16);
    __half*         h16b  = (__half*)(ws + o_h16b);

    hipMemsetAsync(ws, 0, zero_span, stream);

    int gB = (N + 63) / 64;          // 782 gemm tiles
    int rB = (E + 255) / 256;        // 6250 rank chunks
    int nb = (N + 255) / 256;

    // fused: gemm layer-1 || edge ranking || wedot
    gemm1_rank_fused<<<gB + rB + 1, 256, 0, stream>>>(
        x, W1, as1, ad1, h16, ls, ld_, N,
        ei, rank, deg, E,
        We1, ae1, We2, ae2, We3, ae3, wd, gB, rB);

    scan_block<<<nb, 256, 0, stream>>>(deg, rp, bsum, N);
    scan_top<<<1, 256, 0, stream>>>(bsum, nb);
    scan_add<<<(N + 256) / 256, 256, 0, stream>>>(rp, bsum, N, etot);
    scatter_k<<<(E + 255) / 256, 256, 0, stream>>>(ei, ea, rp, rank, csr, E);

    // layer 1 aggregation (writes fp16)
    agg_k<true, false><<<N, 128, 0, stream>>>(h16, ls, ld_, rp, csr, wd, b1,
                                              h16b, nullptr, nullptr, N);
    // layer 2 (+ fused layer-3 projection)
    gemm_lsld<HC, true><<<(N + 63) / 64, 256, 0, stream>>>(h16b, W2, as2, ad2,
                                                           h16, ls, ld_, N);
    agg_k<true, true><<<N, 128, 0, stream>>>(h16, ls, ld_, rp, csr, wd + 4, b2,
                                             nullptr, W3, h3, N);
    // layer 3
    layer3_k<<<(N * 8 + 255) / 256, 256, 0, stream>>>(h3, rp, csr, wd, as3, ad3, b3,
                                                      (float*)d_out, N);
}

// Round 11
// 296.237 us; speedup vs baseline: 1.1167x; 1.0190x over previous
//
#include <hip/hip_runtime.h>
#include <hip/hip_bf16.h>
#include <hip/hip_fp16.h>

#define NNODES 50000
#define NEDGES 1600000
#define ETOT   (NNODES + NEDGES)
#define FIN    256
#define HC     128
#define NEG    0.2f
#define DEGCAP 128
#define ALP    (DEGCAP + 8)

typedef _Float16 h2 __attribute__((ext_vector_type(2)));

__device__ __forceinline__ float fdot2f(h2 a, h2 b, float c) {
#if __has_builtin(__builtin_amdgcn_fdot2)
    return __builtin_amdgcn_fdot2(a, b, c, false);
#else
    return fmaf((float)a.x, (float)b.x, fmaf((float)a.y, (float)b.y, c));
#endif
}

// ---------------- shared GEMM body (fp16 LDS + dot2, fp32 accum, h stored fp16) ----------------
// XH: input matrix is fp16 (row-major [n][K]); otherwise fp32.
template <int K, int BM, bool XH>
__device__ __forceinline__ void gemm_body(
        const void* __restrict__ xv, const float* __restrict__ W,
        const float* __restrict__ a_s, const float* __restrict__ a_d,
        __half* __restrict__ h, float* __restrict__ ls, float* __restrict__ ld_,
        int n, int bid) {
    constexpr int BK = 32;            // k per tile
    constexpr int BKH = BK / 2;       // 16 half2 k-pairs
    constexpr int RM = BM / 8;        // rows per thread (BM=64 -> 8, BM=32 -> 4)
    __shared__ h2 xA[BKH][BM + 2];    // xA[j][m] = (x[m][2j], x[m][2j+1]); pad kills write conflicts
    __shared__ h2 wW[BKH][HC];        // wW[j][c] = (W[2j][c], W[2j+1][c])
    int t = threadIdx.x;
    int tx = t & 31;
    int ty = t >> 5;
    int r0 = bid * BM;

    float acc[RM][4];
#pragma unroll
    for (int r = 0; r < RM; r++)
#pragma unroll
        for (int c = 0; c < 4; c++) acc[r][c] = 0.f;

    for (int kc = 0; kc < K; kc += BK) {
        __syncthreads();
        // stage x tile (BM rows x 32 k), packed in k-pairs
#pragma unroll
        for (int q = 0; q < BM / 32; q++) {
            int idx = q * 256 + t;
            int m = idx >> 3;
            int k4 = (idx & 7) * 4;
            int row = r0 + m;
            float vv[4] = {0.f, 0.f, 0.f, 0.f};
            if (row < n) {
                if constexpr (XH) {
                    const __half* xh = (const __half*)xv;
                    int2 rw = *(const int2*)&xh[(size_t)row * K + kc + k4];
                    float2 f0 = __half22float2(*reinterpret_cast<const __half2*>(&rw.x));
                    float2 f1 = __half22float2(*reinterpret_cast<const __half2*>(&rw.y));
                    vv[0] = f0.x; vv[1] = f0.y; vv[2] = f1.x; vv[3] = f1.y;
                } else {
                    float4 vt = *(const float4*)&((const float*)xv)[(size_t)row * K + kc + k4];
                    vv[0] = vt.x; vv[1] = vt.y; vv[2] = vt.z; vv[3] = vt.w;
                }
            }
            int j0 = k4 >> 1;
            h2 p0, p1;
            p0.x = (_Float16)vv[0]; p0.y = (_Float16)vv[1];
            p1.x = (_Float16)vv[2]; p1.y = (_Float16)vv[3];
            xA[j0][m] = p0;
            xA[j0 + 1][m] = p1;
        }
        // stage W tile (32 k x 128 c), packed in k-pairs
#pragma unroll
        for (int q = 0; q < 2; q++) {
            int idx = q * 256 + t;
            int j = idx >> 5;
            int c4 = (idx & 31) * 4;
            float4 w0 = *(const float4*)&W[(size_t)(kc + 2 * j) * HC + c4];
            float4 w1 = *(const float4*)&W[(size_t)(kc + 2 * j + 1) * HC + c4];
            h2 a, b, c, d;
            a.x = (_Float16)w0.x; a.y = (_Float16)w1.x;
            b.x = (_Float16)w0.y; b.y = (_Float16)w1.y;
            c.x = (_Float16)w0.z; c.y = (_Float16)w1.z;
            d.x = (_Float16)w0.w; d.y = (_Float16)w1.w;
            wW[j][c4] = a; wW[j][c4 + 1] = b; wW[j][c4 + 2] = c; wW[j][c4 + 3] = d;
        }
        __syncthreads();
#pragma unroll
        for (int j = 0; j < BKH; j++) {
            h2 a[RM];
#pragma unroll
            for (int r = 0; r < RM; r++) a[r] = xA[j][RM * ty + r];
            h2 w0 = wW[j][4 * tx], w1 = wW[j][4 * tx + 1];
            h2 w2 = wW[j][4 * tx + 2], w3 = wW[j][4 * tx + 3];
#pragma unroll
            for (int r = 0; r < RM; r++) {
                acc[r][0] = fdot2f(a[r], w0, acc[r][0]);
                acc[r][1] = fdot2f(a[r], w1, acc[r][1]);
                acc[r][2] = fdot2f(a[r], w2, acc[r][2]);
                acc[r][3] = fdot2f(a[r], w3, acc[r][3]);
            }
        }
    }

    int head = tx >> 3;
    float4 sa4 = *(const float4*)&a_s[4 * tx];
    float4 sd4 = *(const float4*)&a_d[4 * tx];
    float sa[4] = {sa4.x, sa4.y, sa4.z, sa4.w};
    float sd[4] = {sd4.x, sd4.y, sd4.z, sd4.w};
#pragma unroll
    for (int r = 0; r < RM; r++) {
        int row = r0 + RM * ty + r;
        if (row >= n) break;
        union { __half2 h2v[2]; int2 i2; } u;
        u.h2v[0] = __floats2half2_rn(acc[r][0], acc[r][1]);
        u.h2v[1] = __floats2half2_rn(acc[r][2], acc[r][3]);
        *(int2*)&h[(size_t)row * HC + 4 * tx] = u.i2;
        float p = acc[r][0] * sa[0] + acc[r][1] * sa[1] + acc[r][2] * sa[2] + acc[r][3] * sa[3];
        float q = acc[r][0] * sd[0] + acc[r][1] * sd[1] + acc[r][2] * sd[2] + acc[r][3] * sd[3];
        p += __shfl_xor(p, 1); q += __shfl_xor(q, 1);
        p += __shfl_xor(p, 2); q += __shfl_xor(q, 2);
        p += __shfl_xor(p, 4); q += __shfl_xor(q, 4);
        if ((tx & 7) == 0) {
            ls[row * 4 + head] = p;
            ld_[row * 4 + head] = q;
        }
    }
}

// ---------------- fused: gemm layer-1 | edge ranking | wedot ----------------
__global__ __launch_bounds__(256) void gemm1_rank_fused(
        const float* __restrict__ x, const float* __restrict__ W,
        const float* __restrict__ a_s, const float* __restrict__ a_d,
        __half* __restrict__ h, float* __restrict__ ls, float* __restrict__ ld_,
        int n,
        const int* __restrict__ ei, unsigned short* __restrict__ rank,
        int* __restrict__ deg, int E,
        const float* We1, const float* ae1, const float* We2, const float* ae2,
        const float* We3, const float* ae3, float* __restrict__ wedot,
        int gB, int rB) {
    int b = blockIdx.x;
    if (b < gB) {
        gemm_body<FIN, 64, false>(x, W, a_s, a_d, h, ls, ld_, n, b);
    } else if (b < gB + rB) {
        int i = (b - gB) * 256 + threadIdx.x;
        if (i < E) rank[i] = (unsigned short)atomicAdd(&deg[ei[E + i]], 1);
    } else {
        int t = threadIdx.x;
        if (t < 128) {
            float p1 = We1[t] * ae1[t];
            float p2 = We2[t] * ae2[t];
            for (int o = 16; o; o >>= 1) {
                p1 += __shfl_xor(p1, o, 32);
                p2 += __shfl_xor(p2, o, 32);
            }
            if ((t & 31) == 0) {
                wedot[t >> 5] = p1;
                wedot[4 + (t >> 5)] = p2;
            }
            if (t == 0) wedot[8] = We3[0] * ae3[0];
        }
    }
}

// standalone gemm (layer 2, fp16 input, BM=32 for occupancy)
template <int K, int BM, bool XH>
__global__ __launch_bounds__(256) void gemm_lsld(
        const void* __restrict__ x, const float* __restrict__ W,
        const float* __restrict__ a_s, const float* __restrict__ a_d,
        __half* __restrict__ h, float* __restrict__ ls, float* __restrict__ ld_,
        int n) {
    gemm_body<K, BM, XH>(x, W, a_s, a_d, h, ls, ld_, n, blockIdx.x);
}

// ---------------- CSR build ----------------

// exclusive scan of (deg[i]+1)  — +1 reserves the self-loop slot per node
__global__ void scan_block(const int* __restrict__ deg, int* __restrict__ out,
                           int* __restrict__ bsum, int n) {
    __shared__ int sh[256];
    int t = threadIdx.x;
    int i = blockIdx.x * 256 + t;
    int v = (i < n) ? (deg[i] + 1) : 0;
    sh[t] = v;
    __syncthreads();
    for (int o = 1; o < 256; o <<= 1) {
        int a = (t >= o) ? sh[t - o] : 0;
        __syncthreads();
        sh[t] += a;
        __syncthreads();
    }
    if (i < n) out[i] = sh[t] - v;
    if (t == 255) bsum[blockIdx.x] = sh[255];
}

__global__ void scan_top(int* __restrict__ bsum, int nb) {
    __shared__ int sh[256];
    int t = threadIdx.x;
    int v = (t < nb) ? bsum[t] : 0;
    sh[t] = v;
    __syncthreads();
    for (int o = 1; o < 256; o <<= 1) {
        int a = (t >= o) ? sh[t - o] : 0;
        __syncthreads();
        sh[t] += a;
        __syncthreads();
    }
    if (t < nb) bsum[t] = sh[t] - v;
}

__global__ void scan_add(int* __restrict__ rp, const int* __restrict__ boff,
                         int n, int etot) {
    int i = blockIdx.x * blockDim.x + threadIdx.x;
    if (i < n)      rp[i] += boff[i >> 8];
    else if (i == n) rp[n] = etot;
}

// atomic-free scatter into packed (src, ea) int2 CSR; last slot per node left unwritten
__global__ void scatter_k(const int* __restrict__ ei, const float* __restrict__ ea,
                          const int* __restrict__ rp, const unsigned short* __restrict__ rank,
                          int2* __restrict__ csr, int E) {
    int i = blockIdx.x * blockDim.x + threadIdx.x;
    if (i < E) {
        int d = ei[E + i];
        int pos = rp[d] + (int)rank[i];
        csr[pos] = make_int2(ei[i], __float_as_int(ea[i]));
    }
}

// ---------------- per-node softmax aggregation (fp16 full-row gather) ----------------
// Self-loop slot (last in segment) synthesized in-wave: src=nid, ea=mean(real ea).
template <bool RELU, bool FUSE3>
__global__ __launch_bounds__(128) void agg_k(
        const __half* __restrict__ h, const float* __restrict__ ls,
        const float* __restrict__ ld_, const int* __restrict__ row_ptr,
        const int2* __restrict__ csr,
        const float* __restrict__ wedot, const float* __restrict__ bias,
        __half* __restrict__ out, const float* __restrict__ W3,
        float* __restrict__ h3, int n) {
    __shared__ float albuf[4][ALP];
    __shared__ int srcbuf[DEGCAP];       // pre-scaled row byte offsets (s*256)
    __shared__ float pacc[8][HC];
    __shared__ float hsuminv[4];
    int nid = blockIdx.x;
    int t = threadIdx.x, head = t >> 5, lane = t & 31;
    int beg = row_ptr[nid], end = row_ptr[nid + 1];
    int deg = end - beg;                 // includes synthetic self-loop slot
    float ldn = ld_[nid * 4 + head];
    float wd = wedot[head];

    float v;
    if (deg <= DEGCAP) {
        int degr = deg - 1;              // real edges
        // phase A: per-head-wave, logits in static registers; easum for self-loop
        float lgr[4];
        float mx = -1e30f, easum = 0.f;
#pragma unroll
        for (int i = 0; i < 4; i++) {
            int e = lane + 32 * i;
            float lg = -1e30f;
            if (e < degr) {
                int2 ce = csr[beg + e];
                if (head == 0) srcbuf[e] = ce.x << 8;   // s * HC * 2 bytes
                float eav = __int_as_float(ce.y);
                easum += eav;
                lg = ls[ce.x * 4 + head] + ldn + eav * wd;
                lg = lg > 0.f ? lg : NEG * lg;
            }
            lgr[i] = lg;
            mx = fmaxf(mx, lg);
        }
        for (int o = 16; o; o >>= 1) {
            easum += __shfl_xor(easum, o, 32);
            mx = fmaxf(mx, __shfl_xor(mx, o, 32));
        }
        // self-loop logit (computed redundantly on all lanes of the wave)
        float mean = easum / fmaxf((float)degr, 1.f);
        float lgs = ls[nid * 4 + head] + ldn + mean * wd;
        lgs = lgs > 0.f ? lgs : NEG * lgs;
        mx = fmaxf(mx, lgs);

        // phase B: exp -> albuf, per-head sum; lane 0 appends self-loop
        float sum = 0.f;
#pragma unroll
        for (int i = 0; i < 4; i++) {
            int e = lane + 32 * i;
            if (e < degr) {
                float p = __expf(lgr[i] - mx);
                albuf[head][e] = p;
                sum += p;
            }
        }
        for (int o = 16; o; o >>= 1) sum += __shfl_xor(sum, o, 32);
        if (lane == 0) {
            float ps = __expf(lgs - mx);
            albuf[head][degr] = ps;
            hsuminv[head] = 1.f / (sum + ps + 1e-16f);
            if (head == 0) srcbuf[degr] = nid << 8;
        }
        __syncthreads();

        // phase C: 8 groups x 16 lanes; group g -> edges g, g+8, ...
        int g = t >> 4, l = t & 15;
        int c0 = 8 * l;
        const float* al = albuf[c0 >> 5];
        const char* hb = (const char*)h + 16 * l;
        float acc[8];
#pragma unroll
        for (int j = 0; j < 8; j++) acc[j] = 0.f;
        int e = g;
        for (; e + 8 < deg; e += 16) {
            int o0 = srcbuf[e], o1 = srcbuf[e + 8];
            int4 r0 = *(const int4*)(hb + o0);
            int4 r1 = *(const int4*)(hb + o1);
            float a0 = al[e], a1 = al[e + 8];
            const __half2* p0 = (const __half2*)&r0;
            const __half2* p1 = (const __half2*)&r1;
#pragma unroll
            for (int j = 0; j < 4; j++) {
                float2 f0 = __half22float2(p0[j]);
                float2 f1 = __half22float2(p1[j]);
                acc[2 * j]     = fmaf(a0, f0.x, acc[2 * j]);
                acc[2 * j + 1] = fmaf(a0, f0.y, acc[2 * j + 1]);
                acc[2 * j]     = fmaf(a1, f1.x, acc[2 * j]);
                acc[2 * j + 1] = fmaf(a1, f1.y, acc[2 * j + 1]);
            }
        }
        for (; e < deg; e += 8) {
            int o0 = srcbuf[e];
            int4 r0 = *(const int4*)(hb + o0);
            float a0 = al[e];
            const __half2* p0 = (const __half2*)&r0;
#pragma unroll
            for (int j = 0; j < 4; j++) {
                float2 f0 = __half22float2(p0[j]);
                acc[2 * j]     = fmaf(a0, f0.x, acc[2 * j]);
                acc[2 * j + 1] = fmaf(a0, f0.y, acc[2 * j + 1]);
            }
        }
#pragma unroll
        for (int j = 0; j < 4; j++)
            *(float2*)&pacc[g][c0 + 2 * j] = make_float2(acc[2 * j], acc[2 * j + 1]);
        __syncthreads();

        float inv = hsuminv[head];
        float sv = pacc[0][t];
#pragma unroll
        for (int g2 = 1; g2 < 8; g2++) sv += pacc[g2][t];
        v = sv * inv + bias[t];
    } else {
        // fallback (deg > DEGCAP): recompute path with synthesized self-loop
        int endr = end - 1;
        float easum = 0.f, mx = -1e30f;
        for (int j = beg + lane; j < endr; j += 32) {
            int2 ce = csr[j];
            float eav = __int_as_float(ce.y);
            easum += eav;
            float lg = ls[ce.x * 4 + head] + ldn + eav * wd;
            lg = lg > 0.f ? lg : NEG * lg;
            mx = fmaxf(mx, lg);
        }
        for (int o = 16; o; o >>= 1) {
            easum += __shfl_xor(easum, o, 32);
            mx = fmaxf(mx, __shfl_xor(mx, o, 32));
        }
        float mean = easum / fmaxf((float)(endr - beg), 1.f);
        float lgs = ls[nid * 4 + head] + ldn + mean * wd;
        lgs = lgs > 0.f ? lgs : NEG * lgs;
        mx = fmaxf(mx, lgs);
        float sum = __expf(lgs - mx);
        float acc = sum * __half2float(h[(size_t)nid * HC + t]);
        for (int j = beg; j < endr; j++) {
            int2 ce = csr[j];
            float lg = ls[ce.x * 4 + head] + ldn + __int_as_float(ce.y) * wd;
            lg = lg > 0.f ? lg : NEG * lg;
            float p = __expf(lg - mx);
            sum += p;
            acc = fmaf(p, __half2float(h[(size_t)ce.x * HC + t]), acc);
        }
        v = acc / (sum + 1e-16f) + bias[t];
        __syncthreads();
        __syncthreads();   // match fast path's barrier count (uniform per block anyway)
    }

    if (RELU) v = fmaxf(v, 0.f);
    if (!FUSE3) out[(size_t)nid * HC + t] = __float2half(v);

    if (FUSE3) {
        float p = v * W3[t];
        for (int o = 32; o; o >>= 1) p += __shfl_xor(p, o, 64);
        __shared__ float sh[2];
        if ((t & 63) == 0) sh[t >> 6] = p;
        __syncthreads();
        if (t == 0) h3[nid] = sh[0] + sh[1];
    }
}

// ---------------- layer 3 (1 head, 1 channel), 8 lanes per node, synth self-loop ----------------
__global__ __launch_bounds__(256) void layer3_k(
        const float* __restrict__ h3, const int* __restrict__ row_ptr,
        const int2* __restrict__ csr,
        const float* __restrict__ wedot, const float* __restrict__ as3,
        const float* __restrict__ ad3, const float* __restrict__ b3,
        float* __restrict__ out, int n) {
    int idx = blockIdx.x * blockDim.x + threadIdx.x;
    int node = idx >> 3, l = idx & 7;
    if (node >= n) return;
    float A = as3[0], D = ad3[0], wd = wedot[8];
    int beg = row_ptr[node], endr = row_ptr[node + 1] - 1;
    float hs = h3[node];
    float hdn = hs * D;

    float easum = 0.f, mx = -1e30f;
    for (int j = beg + l; j < endr; j += 8) {
        int2 ce = csr[j];
        float eav = __int_as_float(ce.y);
        easum += eav;
        float lg = h3[ce.x] * A + hdn + eav * wd;
        lg = lg > 0.f ? lg : NEG * lg;
        mx = fmaxf(mx, lg);
    }
    easum += __shfl_xor(easum, 1, 8); mx = fmaxf(mx, __shfl_xor(mx, 1, 8));
    easum += __shfl_xor(easum, 2, 8); mx = fmaxf(mx, __shfl_xor(mx, 2, 8));
    easum += __shfl_xor(easum, 4, 8); mx = fmaxf(mx, __shfl_xor(mx, 4, 8));
    float mean = easum / fmaxf((float)(endr - beg), 1.f);
    float lgs = hs * A + hdn + mean * wd;
    lgs = lgs > 0.f ? lgs : NEG * lgs;
    mx = fmaxf(mx, lgs);

    float sum = 0.f, num = 0.f;
    for (int j = beg + l; j < endr; j += 8) {
        int2 ce = csr[j];
        float hv = h3[ce.x];
        float lg = hv * A + hdn + __int_as_float(ce.y) * wd;
        lg = lg > 0.f ? lg : NEG * lg;
        float p = __expf(lg - mx);
        sum += p;
        num = fmaf(p, hv, num);
    }
    sum += __shfl_xor(sum, 1, 8); num += __shfl_xor(num, 1, 8);
    sum += __shfl_xor(sum, 2, 8); num += __shfl_xor(num, 2, 8);
    sum += __shfl_xor(sum, 4, 8); num += __shfl_xor(num, 4, 8);
    if (l == 0) {
        float p = __expf(lgs - mx);
        sum += p;
        num = fmaf(p, hs, num);
        out[node] = num / (sum + 1e-16f) + b3[0];
    }
}

// ---------------- launch ----------------

extern "C" void kernel_launch(void* const* d_in, const int* in_sizes, int n_in,
                              void* d_out, int out_size, void* d_ws, size_t ws_size,
                              hipStream_t stream) {
    const float* x   = (const float*)d_in[0];
    const int*   ei  = (const int*)d_in[1];
    const float* ea  = (const float*)d_in[2];
    const float* W1  = (const float*)d_in[3];
    const float* We1 = (const float*)d_in[4];
    const float* as1 = (const float*)d_in[5];
    const float* ad1 = (const float*)d_in[6];
    const float* ae1 = (const float*)d_in[7];
    const float* b1  = (const float*)d_in[8];
    const float* W2  = (const float*)d_in[9];
    const float* We2 = (const float*)d_in[10];
    const float* as2 = (const float*)d_in[11];
    const float* ad2 = (const float*)d_in[12];
    const float* ae2 = (const float*)d_in[13];
    const float* b2  = (const float*)d_in[14];
    const float* W3  = (const float*)d_in[15];
    const float* We3 = (const float*)d_in[16];
    const float* as3 = (const float*)d_in[17];
    const float* ad3 = (const float*)d_in[18];
    const float* ae3 = (const float*)d_in[19];
    const float* b3  = (const float*)d_in[20];

    const int N = NNODES, E = NEDGES, etot = ETOT;

    char* ws = (char*)d_ws;
    size_t o = 0;
    auto alloc = [&](size_t bytes) { size_t r = o; o = (o + bytes + 255) & ~(size_t)255; return r; };
    size_t o_deg   = alloc((size_t)N * 4);
    size_t zero_span = o;
    size_t o_rp    = alloc((size_t)(N + 1) * 4);
    size_t o_bsum  = alloc(256 * 4);
    size_t o_wd    = alloc(16 * 4);
    size_t o_rank  = alloc((size_t)E * 2);        // u16 ranks
    size_t o_csr   = alloc((size_t)etot * 8);
    size_t o_ls    = alloc((size_t)N * 4 * 4);
    size_t o_ld    = alloc((size_t)N * 4 * 4);
    size_t o_h3    = alloc((size_t)N * 4);
    size_t o_h16   = alloc((size_t)N * HC * 2);   // fp16 feature rows (layer 1 then layer 2)
    size_t o_h16b  = alloc((size_t)N * HC * 2);   // fp16 agg-1 output

    int*            deg   = (int*)(ws + o_deg);
    int*            rp    = (int*)(ws + o_rp);
    int*            bsum  = (int*)(ws + o_bsum);
    float*          wd    = (float*)(ws + o_wd);
    unsigned short* rank  = (unsigned short*)(ws + o_rank);
    int2*           csr   = (int2*)(ws + o_csr);
    float*          ls    = (float*)(ws + o_ls);
    float*          ld_   = (float*)(ws + o_ld);
    float*          h3    = (float*)(ws + o_h3);
    __half*         h16   = (__half*)(ws + o_h16);
    __half*         h16b  = (__half*)(ws + o_h16b);

    hipMemsetAsync(ws, 0, zero_span, stream);

    int gB = (N + 63) / 64;          // 782 gemm tiles
    int rB = (E + 255) / 256;        // 6250 rank chunks
    int nb = (N + 255) / 256;

    // fused: gemm layer-1 || edge ranking || wedot
    gemm1_rank_fused<<<gB + rB + 1, 256, 0, stream>>>(
        x, W1, as1, ad1, h16, ls, ld_, N,
        ei, rank, deg, E,
        We1, ae1, We2, ae2, We3, ae3, wd, gB, rB);

    scan_block<<<nb, 256, 0, stream>>>(deg, rp, bsum, N);
    scan_top<<<1, 256, 0, stream>>>(bsum, nb);
    scan_add<<<(N + 256) / 256, 256, 0, stream>>>(rp, bsum, N, etot);
    scatter_k<<<(E + 255) / 256, 256, 0, stream>>>(ei, ea, rp, rank, csr, E);

    // layer 1 aggregation (writes fp16)
    agg_k<true, false><<<N, 128, 0, stream>>>(h16, ls, ld_, rp, csr, wd, b1,
                                              h16b, nullptr, nullptr, N);
    // layer 2 (+ fused layer-3 projection)
    gemm_lsld<HC, 32, true><<<(N + 31) / 32, 256, 0, stream>>>(h16b, W2, as2, ad2,
                                                               h16, ls, ld_, N);
    agg_k<true, true><<<N, 128, 0, stream>>>(h16, ls, ld_, rp, csr, wd + 4, b2,
                                             nullptr, W3, h3, N);
    // layer 3
    layer3_k<<<(N * 8 + 255) / 256, 256, 0, stream>>>(h3, rp, csr, wd, as3, ad3, b3,
                                                      (float*)d_out, N);
}

// Round 12
// 289.626 us; speedup vs baseline: 1.1422x; 1.0228x over previous
//
#include <hip/hip_runtime.h>
#include <hip/hip_bf16.h>
#include <hip/hip_fp16.h>

#define NNODES 50000
#define NEDGES 1600000
#define ETOT   (NNODES + NEDGES)
#define FIN    256
#define HC     128
#define NEG    0.2f
#define DEGCAP 128
#define ALP    (DEGCAP + 8)

typedef _Float16 h2 __attribute__((ext_vector_type(2)));

__device__ __forceinline__ float fdot2f(h2 a, h2 b, float c) {
#if __has_builtin(__builtin_amdgcn_fdot2)
    return __builtin_amdgcn_fdot2(a, b, c, false);
#else
    return fmaf((float)a.x, (float)b.x, fmaf((float)a.y, (float)b.y, c));
#endif
}

// ---------------- shared GEMM body (fp16 LDS + dot2, fp32 accum, h stored fp16) ----------------
template <int K, int BM, bool XH>
__device__ __forceinline__ void gemm_body(
        const void* __restrict__ xv, const float* __restrict__ W,
        const float* __restrict__ a_s, const float* __restrict__ a_d,
        __half* __restrict__ h, float* __restrict__ ls, float* __restrict__ ld_,
        int n, int bid) {
    constexpr int BK = 32;
    constexpr int BKH = BK / 2;
    constexpr int RM = BM / 8;
    __shared__ h2 xA[BKH][BM + 2];
    __shared__ h2 wW[BKH][HC];
    int t = threadIdx.x;
    int tx = t & 31;
    int ty = t >> 5;
    int r0 = bid * BM;

    float acc[RM][4];
#pragma unroll
    for (int r = 0; r < RM; r++)
#pragma unroll
        for (int c = 0; c < 4; c++) acc[r][c] = 0.f;

    for (int kc = 0; kc < K; kc += BK) {
        __syncthreads();
#pragma unroll
        for (int q = 0; q < BM / 32; q++) {
            int idx = q * 256 + t;
            int m = idx >> 3;
            int k4 = (idx & 7) * 4;
            int row = r0 + m;
            float vv[4] = {0.f, 0.f, 0.f, 0.f};
            if (row < n) {
                if constexpr (XH) {
                    const __half* xh = (const __half*)xv;
                    int2 rw = *(const int2*)&xh[(size_t)row * K + kc + k4];
                    float2 f0 = __half22float2(*reinterpret_cast<const __half2*>(&rw.x));
                    float2 f1 = __half22float2(*reinterpret_cast<const __half2*>(&rw.y));
                    vv[0] = f0.x; vv[1] = f0.y; vv[2] = f1.x; vv[3] = f1.y;
                } else {
                    float4 vt = *(const float4*)&((const float*)xv)[(size_t)row * K + kc + k4];
                    vv[0] = vt.x; vv[1] = vt.y; vv[2] = vt.z; vv[3] = vt.w;
                }
            }
            int j0 = k4 >> 1;
            h2 p0, p1;
            p0.x = (_Float16)vv[0]; p0.y = (_Float16)vv[1];
            p1.x = (_Float16)vv[2]; p1.y = (_Float16)vv[3];
            xA[j0][m] = p0;
            xA[j0 + 1][m] = p1;
        }
#pragma unroll
        for (int q = 0; q < 2; q++) {
            int idx = q * 256 + t;
            int j = idx >> 5;
            int c4 = (idx & 31) * 4;
            float4 w0 = *(const float4*)&W[(size_t)(kc + 2 * j) * HC + c4];
            float4 w1 = *(const float4*)&W[(size_t)(kc + 2 * j + 1) * HC + c4];
            h2 a, b, c, d;
            a.x = (_Float16)w0.x; a.y = (_Float16)w1.x;
            b.x = (_Float16)w0.y; b.y = (_Float16)w1.y;
            c.x = (_Float16)w0.z; c.y = (_Float16)w1.z;
            d.x = (_Float16)w0.w; d.y = (_Float16)w1.w;
            wW[j][c4] = a; wW[j][c4 + 1] = b; wW[j][c4 + 2] = c; wW[j][c4 + 3] = d;
        }
        __syncthreads();
#pragma unroll
        for (int j = 0; j < BKH; j++) {
            h2 a[RM];
#pragma unroll
            for (int r = 0; r < RM; r++) a[r] = xA[j][RM * ty + r];
            h2 w0 = wW[j][4 * tx], w1 = wW[j][4 * tx + 1];
            h2 w2 = wW[j][4 * tx + 2], w3 = wW[j][4 * tx + 3];
#pragma unroll
            for (int r = 0; r < RM; r++) {
                acc[r][0] = fdot2f(a[r], w0, acc[r][0]);
                acc[r][1] = fdot2f(a[r], w1, acc[r][1]);
                acc[r][2] = fdot2f(a[r], w2, acc[r][2]);
                acc[r][3] = fdot2f(a[r], w3, acc[r][3]);
            }
        }
    }

    int head = tx >> 3;
    float4 sa4 = *(const float4*)&a_s[4 * tx];
    float4 sd4 = *(const float4*)&a_d[4 * tx];
    float sa[4] = {sa4.x, sa4.y, sa4.z, sa4.w};
    float sd[4] = {sd4.x, sd4.y, sd4.z, sd4.w};
#pragma unroll
    for (int r = 0; r < RM; r++) {
        int row = r0 + RM * ty + r;
        if (row >= n) break;
        union { __half2 h2v[2]; int2 i2; } u;
        u.h2v[0] = __floats2half2_rn(acc[r][0], acc[r][1]);
        u.h2v[1] = __floats2half2_rn(acc[r][2], acc[r][3]);
        *(int2*)&h[(size_t)row * HC + 4 * tx] = u.i2;
        float p = acc[r][0] * sa[0] + acc[r][1] * sa[1] + acc[r][2] * sa[2] + acc[r][3] * sa[3];
        float q = acc[r][0] * sd[0] + acc[r][1] * sd[1] + acc[r][2] * sd[2] + acc[r][3] * sd[3];
        p += __shfl_xor(p, 1); q += __shfl_xor(q, 1);
        p += __shfl_xor(p, 2); q += __shfl_xor(q, 2);
        p += __shfl_xor(p, 4); q += __shfl_xor(q, 4);
        if ((tx & 7) == 0) {
            ls[row * 4 + head] = p;
            ld_[row * 4 + head] = q;
        }
    }
}

// ---------------- fused: gemm layer-1 | edge ranking | wedot ----------------
__global__ __launch_bounds__(256) void gemm1_rank_fused(
        const float* __restrict__ x, const float* __restrict__ W,
        const float* __restrict__ a_s, const float* __restrict__ a_d,
        __half* __restrict__ h, float* __restrict__ ls, float* __restrict__ ld_,
        int n,
        const int* __restrict__ ei, unsigned short* __restrict__ rank,
        int* __restrict__ deg, int E,
        const float* We1, const float* ae1, const float* We2, const float* ae2,
        const float* We3, const float* ae3, float* __restrict__ wedot,
        int gB, int rB) {
    int b = blockIdx.x;
    if (b < gB) {
        gemm_body<FIN, 64, false>(x, W, a_s, a_d, h, ls, ld_, n, b);
    } else if (b < gB + rB) {
        int i = (b - gB) * 256 + threadIdx.x;
        if (i < E) rank[i] = (unsigned short)atomicAdd(&deg[ei[E + i]], 1);
    } else {
        int t = threadIdx.x;
        if (t < 128) {
            float p1 = We1[t] * ae1[t];
            float p2 = We2[t] * ae2[t];
            for (int o = 16; o; o >>= 1) {
                p1 += __shfl_xor(p1, o, 32);
                p2 += __shfl_xor(p2, o, 32);
            }
            if ((t & 31) == 0) {
                wedot[t >> 5] = p1;
                wedot[4 + (t >> 5)] = p2;
            }
            if (t == 0) wedot[8] = We3[0] * ae3[0];
        }
    }
}

// standalone gemm (layer 2, fp16 input, BM=32 for occupancy)
template <int K, int BM, bool XH>
__global__ __launch_bounds__(256) void gemm_lsld(
        const void* __restrict__ x, const float* __restrict__ W,
        const float* __restrict__ a_s, const float* __restrict__ a_d,
        __half* __restrict__ h, float* __restrict__ ls, float* __restrict__ ld_,
        int n) {
    gemm_body<K, BM, XH>(x, W, a_s, a_d, h, ls, ld_, n, blockIdx.x);
}

// ---------------- CSR build ----------------

// exclusive scan of (deg[i]+1); also emits rp[n] (block-partial; boff added downstream)
__global__ void scan_block(const int* __restrict__ deg, int* __restrict__ out,
                           int* __restrict__ bsum, int n) {
    __shared__ int sh[256];
    int t = threadIdx.x;
    int i = blockIdx.x * 256 + t;
    int v = (i < n) ? (deg[i] + 1) : 0;
    sh[t] = v;
    __syncthreads();
    for (int o = 1; o < 256; o <<= 1) {
        int a = (t >= o) ? sh[t - o] : 0;
        __syncthreads();
        sh[t] += a;
        __syncthreads();
    }
    if (i <= n) out[i] = sh[t] - v;
    if (t == 255) bsum[blockIdx.x] = sh[255];
}

__global__ void scan_top(int* __restrict__ bsum, int nb) {
    __shared__ int sh[256];
    int t = threadIdx.x;
    int v = (t < nb) ? bsum[t] : 0;
    sh[t] = v;
    __syncthreads();
    for (int o = 1; o < 256; o <<= 1) {
        int a = (t >= o) ? sh[t - o] : 0;
        __syncthreads();
        sh[t] += a;
        __syncthreads();
    }
    if (t < nb) bsum[t] = sh[t] - v;
}

// atomic-free scatter into packed (src, ea) int2 CSR; boff folded inline
__global__ void scatter_k(const int* __restrict__ ei, const float* __restrict__ ea,
                          const int* __restrict__ rp, const int* __restrict__ boff,
                          const unsigned short* __restrict__ rank,
                          int2* __restrict__ csr, int E) {
    int i = blockIdx.x * blockDim.x + threadIdx.x;
    if (i < E) {
        int d = ei[E + i];
        int pos = rp[d] + boff[d >> 8] + (int)rank[i];
        csr[pos] = make_int2(ei[i], __float_as_int(ea[i]));
    }
}

// ---------------- per-node softmax aggregation (fp16 full-row gather) ----------------
// Self-loop slot (last in segment) synthesized in-wave: src=nid, ea=mean(real ea).
template <bool RELU, bool FUSE3>
__global__ __launch_bounds__(128) void agg_k(
        const __half* __restrict__ h, const float* __restrict__ ls,
        const float* __restrict__ ld_, const int* __restrict__ rp,
        const int* __restrict__ boff, const int2* __restrict__ csr,
        const float* __restrict__ wedot, const float* __restrict__ bias,
        __half* __restrict__ out, const float* __restrict__ W3,
        float* __restrict__ h3, int n) {
    __shared__ float albuf[4][ALP];
    __shared__ int srcbuf[DEGCAP];       // pre-scaled row byte offsets (s*256)
    __shared__ float pacc[8][HC];
    __shared__ float hsuminv[4];
    int nid = blockIdx.x;
    int t = threadIdx.x, head = t >> 5, lane = t & 31;
    int beg = rp[nid] + boff[nid >> 8];
    int end = rp[nid + 1] + boff[(nid + 1) >> 8];
    int deg = end - beg;                 // includes synthetic self-loop slot
    float ldn = ld_[nid * 4 + head];
    float wd = wedot[head];

    float v;
    if (deg <= DEGCAP) {
        int degr = deg - 1;              // real edges
        // phase A: per-head-wave, logits in static registers; easum for self-loop
        float lgr[4];
        float mx = -1e30f, easum = 0.f;
#pragma unroll
        for (int i = 0; i < 4; i++) {
            int e = lane + 32 * i;
            float lg = -1e30f;
            if (e < degr) {
                int2 ce = csr[beg + e];
                if (head == 0) srcbuf[e] = ce.x << 8;   // s * HC * 2 bytes
                float eav = __int_as_float(ce.y);
                easum += eav;
                lg = ls[ce.x * 4 + head] + ldn + eav * wd;
                lg = lg > 0.f ? lg : NEG * lg;
            }
            lgr[i] = lg;
            mx = fmaxf(mx, lg);
        }
        for (int o = 16; o; o >>= 1) {
            easum += __shfl_xor(easum, o, 32);
            mx = fmaxf(mx, __shfl_xor(mx, o, 32));
        }
        float mean = easum / fmaxf((float)degr, 1.f);
        float lgs = ls[nid * 4 + head] + ldn + mean * wd;
        lgs = lgs > 0.f ? lgs : NEG * lgs;
        mx = fmaxf(mx, lgs);

        // phase B: exp -> albuf, per-head sum; lane 0 appends self-loop
        float sum = 0.f;
#pragma unroll
        for (int i = 0; i < 4; i++) {
            int e = lane + 32 * i;
            if (e < degr) {
                float p = __expf(lgr[i] - mx);
                albuf[head][e] = p;
                sum += p;
            }
        }
        for (int o = 16; o; o >>= 1) sum += __shfl_xor(sum, o, 32);
        if (lane == 0) {
            float ps = __expf(lgs - mx);
            albuf[head][degr] = ps;
            hsuminv[head] = 1.f / (sum + ps + 1e-16f);
            if (head == 0) srcbuf[degr] = nid << 8;
        }
        __syncthreads();

        // phase C: 8 groups x 16 lanes; group g -> edges g, g+8, ...; unroll-4 for MLP
        int g = t >> 4, l = t & 15;
        int c0 = 8 * l;
        const float* al = albuf[c0 >> 5];
        const char* hb = (const char*)h + 16 * l;
        float acc[8];
#pragma unroll
        for (int j = 0; j < 8; j++) acc[j] = 0.f;
        for (int e0 = g; e0 < deg; e0 += 32) {
            int e1 = e0 + 8, e2 = e0 + 16, e3 = e0 + 24;
            bool v1 = e1 < deg, v2 = e2 < deg, v3 = e3 < deg;
            int i1 = v1 ? e1 : 0, i2 = v2 ? e2 : 0, i3 = v3 ? e3 : 0;
            int o0 = srcbuf[e0], o1 = srcbuf[i1], o2 = srcbuf[i2], o3 = srcbuf[i3];
            int4 r0 = *(const int4*)(hb + o0);
            int4 r1 = *(const int4*)(hb + o1);
            int4 r2 = *(const int4*)(hb + o2);
            int4 r3 = *(const int4*)(hb + o3);
            float a0 = al[e0];
            float a1 = al[i1]; a1 = v1 ? a1 : 0.f;
            float a2 = al[i2]; a2 = v2 ? a2 : 0.f;
            float a3 = al[i3]; a3 = v3 ? a3 : 0.f;
            const __half2* p0 = (const __half2*)&r0;
            const __half2* p1 = (const __half2*)&r1;
            const __half2* p2 = (const __half2*)&r2;
            const __half2* p3 = (const __half2*)&r3;
#pragma unroll
            for (int j = 0; j < 4; j++) {
                float2 f0 = __half22float2(p0[j]);
                float2 f1 = __half22float2(p1[j]);
                float2 f2 = __half22float2(p2[j]);
                float2 f3 = __half22float2(p3[j]);
                acc[2 * j]     = fmaf(a0, f0.x, acc[2 * j]);
                acc[2 * j + 1] = fmaf(a0, f0.y, acc[2 * j + 1]);
                acc[2 * j]     = fmaf(a1, f1.x, acc[2 * j]);
                acc[2 * j + 1] = fmaf(a1, f1.y, acc[2 * j + 1]);
                acc[2 * j]     = fmaf(a2, f2.x, acc[2 * j]);
                acc[2 * j + 1] = fmaf(a2, f2.y, acc[2 * j + 1]);
                acc[2 * j]     = fmaf(a3, f3.x, acc[2 * j]);
                acc[2 * j + 1] = fmaf(a3, f3.y, acc[2 * j + 1]);
            }
        }
#pragma unroll
        for (int j = 0; j < 4; j++)
            *(float2*)&pacc[g][c0 + 2 * j] = make_float2(acc[2 * j], acc[2 * j + 1]);
        __syncthreads();

        float inv = hsuminv[head];
        float sv = pacc[0][t];
#pragma unroll
        for (int g2 = 1; g2 < 8; g2++) sv += pacc[g2][t];
        v = sv * inv + bias[t];
    } else {
        // fallback (deg > DEGCAP): recompute path with synthesized self-loop
        int endr = end - 1;
        float easum = 0.f, mx = -1e30f;
        for (int j = beg + lane; j < endr; j += 32) {
            int2 ce = csr[j];
            float eav = __int_as_float(ce.y);
            easum += eav;
            float lg = ls[ce.x * 4 + head] + ldn + eav * wd;
            lg = lg > 0.f ? lg : NEG * lg;
            mx = fmaxf(mx, lg);
        }
        for (int o = 16; o; o >>= 1) {
            easum += __shfl_xor(easum, o, 32);
            mx = fmaxf(mx, __shfl_xor(mx, o, 32));
        }
        float mean = easum / fmaxf((float)(endr - beg), 1.f);
        float lgs = ls[nid * 4 + head] + ldn + mean * wd;
        lgs = lgs > 0.f ? lgs : NEG * lgs;
        mx = fmaxf(mx, lgs);
        float sum = __expf(lgs - mx);
        float acc = sum * __half2float(h[(size_t)nid * HC + t]);
        for (int j = beg; j < endr; j++) {
            int2 ce = csr[j];
            float lg = ls[ce.x * 4 + head] + ldn + __int_as_float(ce.y) * wd;
            lg = lg > 0.f ? lg : NEG * lg;
            float p = __expf(lg - mx);
            sum += p;
            acc = fmaf(p, __half2float(h[(size_t)ce.x * HC + t]), acc);
        }
        v = acc / (sum + 1e-16f) + bias[t];
        __syncthreads();
        __syncthreads();
    }

    if (RELU) v = fmaxf(v, 0.f);
    if (!FUSE3) out[(size_t)nid * HC + t] = __float2half(v);

    if (FUSE3) {
        float p = v * W3[t];
        for (int o = 32; o; o >>= 1) p += __shfl_xor(p, o, 64);
        __shared__ float sh[2];
        if ((t & 63) == 0) sh[t >> 6] = p;
        __syncthreads();
        if (t == 0) h3[nid] = sh[0] + sh[1];
    }
}

// ---------------- layer 3 (1 head, 1 channel), 8 lanes per node, synth self-loop ----------------
__global__ __launch_bounds__(256) void layer3_k(
        const float* __restrict__ h3, const int* __restrict__ rp,
        const int* __restrict__ boff, const int2* __restrict__ csr,
        const float* __restrict__ wedot, const float* __restrict__ as3,
        const float* __restrict__ ad3, const float* __restrict__ b3,
        float* __restrict__ out, int n) {
    int idx = blockIdx.x * blockDim.x + threadIdx.x;
    int node = idx >> 3, l = idx & 7;
    if (node >= n) return;
    float A = as3[0], D = ad3[0], wd = wedot[8];
    int beg = rp[node] + boff[node >> 8];
    int endr = rp[node + 1] + boff[(node + 1) >> 8] - 1;
    float hs = h3[node];
    float hdn = hs * D;

    float easum = 0.f, mx = -1e30f;
    for (int j = beg + l; j < endr; j += 8) {
        int2 ce = csr[j];
        float eav = __int_as_float(ce.y);
        easum += eav;
        float lg = h3[ce.x] * A + hdn + eav * wd;
        lg = lg > 0.f ? lg : NEG * lg;
        mx = fmaxf(mx, lg);
    }
    easum += __shfl_xor(easum, 1, 8); mx = fmaxf(mx, __shfl_xor(mx, 1, 8));
    easum += __shfl_xor(easum, 2, 8); mx = fmaxf(mx, __shfl_xor(mx, 2, 8));
    easum += __shfl_xor(easum, 4, 8); mx = fmaxf(mx, __shfl_xor(mx, 4, 8));
    float mean = easum / fmaxf((float)(endr - beg), 1.f);
    float lgs = hs * A + hdn + mean * wd;
    lgs = lgs > 0.f ? lgs : NEG * lgs;
    mx = fmaxf(mx, lgs);

    float sum = 0.f, num = 0.f;
    for (int j = beg + l; j < endr; j += 8) {
        int2 ce = csr[j];
        float hv = h3[ce.x];
        float lg = hv * A + hdn + __int_as_float(ce.y) * wd;
        lg = lg > 0.f ? lg : NEG * lg;
        float p = __expf(lg - mx);
        sum += p;
        num = fmaf(p, hv, num);
    }
    sum += __shfl_xor(sum, 1, 8); num += __shfl_xor(num, 1, 8);
    sum += __shfl_xor(sum, 2, 8); num += __shfl_xor(num, 2, 8);
    sum += __shfl_xor(sum, 4, 8); num += __shfl_xor(num, 4, 8);
    if (l == 0) {
        float p = __expf(lgs - mx);
        sum += p;
        num = fmaf(p, hs, num);
        out[node] = num / (sum + 1e-16f) + b3[0];
    }
}

// ---------------- launch ----------------

extern "C" void kernel_launch(void* const* d_in, const int* in_sizes, int n_in,
                              void* d_out, int out_size, void* d_ws, size_t ws_size,
                              hipStream_t stream) {
    const float* x   = (const float*)d_in[0];
    const int*   ei  = (const int*)d_in[1];
    const float* ea  = (const float*)d_in[2];
    const float* W1  = (const float*)d_in[3];
    const float* We1 = (const float*)d_in[4];
    const float* as1 = (const float*)d_in[5];
    const float* ad1 = (const float*)d_in[6];
    const float* ae1 = (const float*)d_in[7];
    const float* b1  = (const float*)d_in[8];
    const float* W2  = (const float*)d_in[9];
    const float* We2 = (const float*)d_in[10];
    const float* as2 = (const float*)d_in[11];
    const float* ad2 = (const float*)d_in[12];
    const float* ae2 = (const float*)d_in[13];
    const float* b2  = (const float*)d_in[14];
    const float* W3  = (const float*)d_in[15];
    const float* We3 = (const float*)d_in[16];
    const float* as3 = (const float*)d_in[17];
    const float* ad3 = (const float*)d_in[18];
    const float* ae3 = (const float*)d_in[19];
    const float* b3  = (const float*)d_in[20];

    const int N = NNODES, E = NEDGES, etot = ETOT;

    char* ws = (char*)d_ws;
    size_t o = 0;
    auto alloc = [&](size_t bytes) { size_t r = o; o = (o + bytes + 255) & ~(size_t)255; return r; };
    size_t o_deg   = alloc((size_t)N * 4);
    size_t zero_span = o;
    size_t o_rp    = alloc((size_t)(N + 1) * 4);
    size_t o_bsum  = alloc(256 * 4);
    size_t o_wd    = alloc(16 * 4);
    size_t o_rank  = alloc((size_t)E * 2);        // u16 ranks
    size_t o_csr   = alloc((size_t)etot * 8);
    size_t o_ls    = alloc((size_t)N * 4 * 4);
    size_t o_ld    = alloc((size_t)N * 4 * 4);
    size_t o_h3    = alloc((size_t)N * 4);
    size_t o_h16   = alloc((size_t)N * HC * 2);   // fp16 feature rows (layer 1 then layer 2)
    size_t o_h16b  = alloc((size_t)N * HC * 2);   // fp16 agg-1 output

    int*            deg   = (int*)(ws + o_deg);
    int*            rp    = (int*)(ws + o_rp);
    int*            bsum  = (int*)(ws + o_bsum);
    float*          wd    = (float*)(ws + o_wd);
    unsigned short* rank  = (unsigned short*)(ws + o_rank);
    int2*           csr   = (int2*)(ws + o_csr);
    float*          ls    = (float*)(ws + o_ls);
    float*          ld_   = (float*)(ws + o_ld);
    float*          h3    = (float*)(ws + o_h3);
    __half*         h16   = (__half*)(ws + o_h16);
    __half*         h16b  = (__half*)(ws + o_h16b);

    hipMemsetAsync(ws, 0, zero_span, stream);

    int gB = (N + 63) / 64;          // 782 gemm tiles
    int rB = (E + 255) / 256;        // 6250 rank chunks
    int nb = (N + 255) / 256;

    // fused: gemm layer-1 || edge ranking || wedot
    gemm1_rank_fused<<<gB + rB + 1, 256, 0, stream>>>(
        x, W1, as1, ad1, h16, ls, ld_, N,
        ei, rank, deg, E,
        We1, ae1, We2, ae2, We3, ae3, wd, gB, rB);

    scan_block<<<nb, 256, 0, stream>>>(deg, rp, bsum, N);
    scan_top<<<1, 256, 0, stream>>>(bsum, nb);
    scatter_k<<<(E + 255) / 256, 256, 0, stream>>>(ei, ea, rp, bsum, rank, csr, E);

    // layer 1 aggregation (writes fp16)
    agg_k<true, false><<<N, 128, 0, stream>>>(h16, ls, ld_, rp, bsum, csr, wd, b1,
                                              h16b, nullptr, nullptr, N);
    // layer 2 (+ fused layer-3 projection)
    gemm_lsld<HC, 32, true><<<(N + 31) / 32, 256, 0, stream>>>(h16b, W2, as2, ad2,
                                                               h16, ls, ld_, N);
    agg_k<true, true><<<N, 128, 0, stream>>>(h16, ls, ld_, rp, bsum, csr, wd + 4, b2,
                                             nullptr, W3, h3, N);
    // layer 3
    layer3_k<<<(N * 8 + 255) / 256, 256, 0, stream>>>(h3, rp, bsum, csr, wd, as3, ad3, b3,
                                                      (float*)d_out, N);
}

// Round 13
// 287.306 us; speedup vs baseline: 1.1514x; 1.0081x over previous
//
#include <hip/hip_runtime.h>
#include <hip/hip_bf16.h>
#include <hip/hip_fp16.h>

#define NNODES 50000
#define NEDGES 1600000
#define ETOT   (NNODES + NEDGES)
#define FIN    256
#define HC     128
#define NEG    0.2f
#define DEGCAP 128
#define ALP    (DEGCAP + 8)
#define NREP   8

typedef _Float16 h2 __attribute__((ext_vector_type(2)));

__device__ __forceinline__ float fdot2f(h2 a, h2 b, float c) {
#if __has_builtin(__builtin_amdgcn_fdot2)
    return __builtin_amdgcn_fdot2(a, b, c, false);
#else
    return fmaf((float)a.x, (float)b.x, fmaf((float)a.y, (float)b.y, c));
#endif
}

// ---------------- shared GEMM body (fp16 LDS + dot2, fp32 accum, h stored fp16) ----------------
template <int K, int BM, bool XH>
__device__ __forceinline__ void gemm_body(
        const void* __restrict__ xv, const float* __restrict__ W,
        const float* __restrict__ a_s, const float* __restrict__ a_d,
        __half* __restrict__ h, float* __restrict__ ls, float* __restrict__ ld_,
        int n, int bid) {
    constexpr int BK = 32;
    constexpr int BKH = BK / 2;
    constexpr int RM = BM / 8;
    __shared__ h2 xA[BKH][BM + 2];
    __shared__ h2 wW[BKH][HC];
    int t = threadIdx.x;
    int tx = t & 31;
    int ty = t >> 5;
    int r0 = bid * BM;

    float acc[RM][4];
#pragma unroll
    for (int r = 0; r < RM; r++)
#pragma unroll
        for (int c = 0; c < 4; c++) acc[r][c] = 0.f;

    for (int kc = 0; kc < K; kc += BK) {
        __syncthreads();
#pragma unroll
        for (int q = 0; q < BM / 32; q++) {
            int idx = q * 256 + t;
            int m = idx >> 3;
            int k4 = (idx & 7) * 4;
            int row = r0 + m;
            float vv[4] = {0.f, 0.f, 0.f, 0.f};
            if (row < n) {
                if constexpr (XH) {
                    const __half* xh = (const __half*)xv;
                    int2 rw = *(const int2*)&xh[(size_t)row * K + kc + k4];
                    float2 f0 = __half22float2(*reinterpret_cast<const __half2*>(&rw.x));
                    float2 f1 = __half22float2(*reinterpret_cast<const __half2*>(&rw.y));
                    vv[0] = f0.x; vv[1] = f0.y; vv[2] = f1.x; vv[3] = f1.y;
                } else {
                    float4 vt = *(const float4*)&((const float*)xv)[(size_t)row * K + kc + k4];
                    vv[0] = vt.x; vv[1] = vt.y; vv[2] = vt.z; vv[3] = vt.w;
                }
            }
            int j0 = k4 >> 1;
            h2 p0, p1;
            p0.x = (_Float16)vv[0]; p0.y = (_Float16)vv[1];
            p1.x = (_Float16)vv[2]; p1.y = (_Float16)vv[3];
            xA[j0][m] = p0;
            xA[j0 + 1][m] = p1;
        }
#pragma unroll
        for (int q = 0; q < 2; q++) {
            int idx = q * 256 + t;
            int j = idx >> 5;
            int c4 = (idx & 31) * 4;
            float4 w0 = *(const float4*)&W[(size_t)(kc + 2 * j) * HC + c4];
            float4 w1 = *(const float4*)&W[(size_t)(kc + 2 * j + 1) * HC + c4];
            h2 a, b, c, d;
            a.x = (_Float16)w0.x; a.y = (_Float16)w1.x;
            b.x = (_Float16)w0.y; b.y = (_Float16)w1.y;
            c.x = (_Float16)w0.z; c.y = (_Float16)w1.z;
            d.x = (_Float16)w0.w; d.y = (_Float16)w1.w;
            wW[j][c4] = a; wW[j][c4 + 1] = b; wW[j][c4 + 2] = c; wW[j][c4 + 3] = d;
        }
        __syncthreads();
#pragma unroll
        for (int j = 0; j < BKH; j++) {
            h2 a[RM];
#pragma unroll
            for (int r = 0; r < RM; r++) a[r] = xA[j][RM * ty + r];
            h2 w0 = wW[j][4 * tx], w1 = wW[j][4 * tx + 1];
            h2 w2 = wW[j][4 * tx + 2], w3 = wW[j][4 * tx + 3];
#pragma unroll
            for (int r = 0; r < RM; r++) {
                acc[r][0] = fdot2f(a[r], w0, acc[r][0]);
                acc[r][1] = fdot2f(a[r], w1, acc[r][1]);
                acc[r][2] = fdot2f(a[r], w2, acc[r][2]);
                acc[r][3] = fdot2f(a[r], w3, acc[r][3]);
            }
        }
    }

    int head = tx >> 3;
    float4 sa4 = *(const float4*)&a_s[4 * tx];
    float4 sd4 = *(const float4*)&a_d[4 * tx];
    float sa[4] = {sa4.x, sa4.y, sa4.z, sa4.w};
    float sd[4] = {sd4.x, sd4.y, sd4.z, sd4.w};
#pragma unroll
    for (int r = 0; r < RM; r++) {
        int row = r0 + RM * ty + r;
        if (row >= n) break;
        union { __half2 h2v[2]; int2 i2; } u;
        u.h2v[0] = __floats2half2_rn(acc[r][0], acc[r][1]);
        u.h2v[1] = __floats2half2_rn(acc[r][2], acc[r][3]);
        *(int2*)&h[(size_t)row * HC + 4 * tx] = u.i2;
        float p = acc[r][0] * sa[0] + acc[r][1] * sa[1] + acc[r][2] * sa[2] + acc[r][3] * sa[3];
        float q = acc[r][0] * sd[0] + acc[r][1] * sd[1] + acc[r][2] * sd[2] + acc[r][3] * sd[3];
        p += __shfl_xor(p, 1); q += __shfl_xor(q, 1);
        p += __shfl_xor(p, 2); q += __shfl_xor(q, 2);
        p += __shfl_xor(p, 4); q += __shfl_xor(q, 4);
        if ((tx & 7) == 0) {
            ls[row * 4 + head] = p;
            ld_[row * 4 + head] = q;
        }
    }
}

// ---------------- fused: gemm layer-1 | edge ranking (8-way replicated) | wedot ----------------
__global__ __launch_bounds__(256) void gemm1_rank_fused(
        const float* __restrict__ x, const float* __restrict__ W,
        const float* __restrict__ a_s, const float* __restrict__ a_d,
        __half* __restrict__ h, float* __restrict__ ls, float* __restrict__ ld_,
        int n,
        const int* __restrict__ ei, unsigned short* __restrict__ rank,
        int* __restrict__ deg8, int E,
        const float* We1, const float* ae1, const float* We2, const float* ae2,
        const float* We3, const float* ae3, float* __restrict__ wedot,
        int gB, int rB) {
    int b = blockIdx.x;
    if (b < gB) {
        gemm_body<FIN, 64, false>(x, W, a_s, a_d, h, ls, ld_, n, b);
    } else if (b < gB + rB) {
        int chunk = b - gB;
        int i = chunk * 256 + threadIdx.x;
        if (i < E) {
            int d = ei[E + i];
            rank[i] = (unsigned short)atomicAdd(&deg8[(chunk & (NREP - 1)) * n + d], 1);
        }
    } else {
        int t = threadIdx.x;
        if (t < 128) {
            float p1 = We1[t] * ae1[t];
            float p2 = We2[t] * ae2[t];
            for (int o = 16; o; o >>= 1) {
                p1 += __shfl_xor(p1, o, 32);
                p2 += __shfl_xor(p2, o, 32);
            }
            if ((t & 31) == 0) {
                wedot[t >> 5] = p1;
                wedot[4 + (t >> 5)] = p2;
            }
            if (t == 0) wedot[8] = We3[0] * ae3[0];
        }
    }
}

// standalone gemm (layer 2, fp16 input, BM=32 for occupancy)
template <int K, int BM, bool XH>
__global__ __launch_bounds__(256) void gemm_lsld(
        const void* __restrict__ x, const float* __restrict__ W,
        const float* __restrict__ a_s, const float* __restrict__ a_d,
        __half* __restrict__ h, float* __restrict__ ls, float* __restrict__ ld_,
        int n) {
    gemm_body<K, BM, XH>(x, W, a_s, a_d, h, ls, ld_, n, blockIdx.x);
}

// ---------------- CSR build ----------------

// combine replicas + exclusive scan of (deg[i]+1); block-partial (boff added downstream)
__global__ void scan_block(const int* __restrict__ deg8, int* __restrict__ off8,
                           int* __restrict__ out, int* __restrict__ bsum, int n) {
    __shared__ int sh[256];
    int t = threadIdx.x;
    int i = blockIdx.x * 256 + t;
    int v = 0;
    if (i < n) {
        int s = 0;
#pragma unroll
        for (int r = 0; r < NREP; r++) {
            int dr = deg8[r * n + i];
            off8[r * n + i] = s;     // edges of node i in replicas < r
            s += dr;
        }
        v = s + 1;                   // +1 reserves the self-loop slot
    }
    sh[t] = v;
    __syncthreads();
    for (int o = 1; o < 256; o <<= 1) {
        int a = (t >= o) ? sh[t - o] : 0;
        __syncthreads();
        sh[t] += a;
        __syncthreads();
    }
    if (i <= n) out[i] = sh[t] - v;
    if (t == 255) bsum[blockIdx.x] = sh[255];
}

__global__ void scan_top(int* __restrict__ bsum, int nb) {
    __shared__ int sh[256];
    int t = threadIdx.x;
    int v = (t < nb) ? bsum[t] : 0;
    sh[t] = v;
    __syncthreads();
    for (int o = 1; o < 256; o <<= 1) {
        int a = (t >= o) ? sh[t - o] : 0;
        __syncthreads();
        sh[t] += a;
        __syncthreads();
    }
    if (t < nb) bsum[t] = sh[t] - v;
}

// atomic-free scatter into packed (src, ea) int2 CSR; replica offset folded in
__global__ void scatter_k(const int* __restrict__ ei, const float* __restrict__ ea,
                          const int* __restrict__ rp, const int* __restrict__ boff,
                          const int* __restrict__ off8,
                          const unsigned short* __restrict__ rank,
                          int2* __restrict__ csr, int E, int n) {
    int i = blockIdx.x * blockDim.x + threadIdx.x;
    if (i < E) {
        int d = ei[E + i];
        int r = (i >> 8) & (NREP - 1);
        int pos = rp[d] + boff[d >> 8] + off8[r * n + d] + (int)rank[i];
        csr[pos] = make_int2(ei[i], __float_as_int(ea[i]));
    }
}

// ---------------- per-node softmax aggregation (fp16 full-row gather) ----------------
template <bool RELU, bool FUSE3>
__global__ __launch_bounds__(128) void agg_k(
        const __half* __restrict__ h, const float* __restrict__ ls,
        const float* __restrict__ ld_, const int* __restrict__ rp,
        const int* __restrict__ boff, const int2* __restrict__ csr,
        const float* __restrict__ wedot, const float* __restrict__ bias,
        __half* __restrict__ out, const float* __restrict__ W3,
        float* __restrict__ h3, int n) {
    __shared__ float albuf[4][ALP];
    __shared__ int srcbuf[DEGCAP];
    __shared__ float pacc[8][HC];
    __shared__ float hsuminv[4];
    int nid = blockIdx.x;
    int t = threadIdx.x, head = t >> 5, lane = t & 31;
    int beg = rp[nid] + boff[nid >> 8];
    int end = rp[nid + 1] + boff[(nid + 1) >> 8];
    int deg = end - beg;
    float ldn = ld_[nid * 4 + head];
    float wd = wedot[head];

    float v;
    if (deg <= DEGCAP) {
        int degr = deg - 1;
        float lgr[4];
        float mx = -1e30f, easum = 0.f;
#pragma unroll
        for (int i = 0; i < 4; i++) {
            int e = lane + 32 * i;
            float lg = -1e30f;
            if (e < degr) {
                int2 ce = csr[beg + e];
                if (head == 0) srcbuf[e] = ce.x << 8;
                float eav = __int_as_float(ce.y);
                easum += eav;
                lg = ls[ce.x * 4 + head] + ldn + eav * wd;
                lg = lg > 0.f ? lg : NEG * lg;
            }
            lgr[i] = lg;
            mx = fmaxf(mx, lg);
        }
        for (int o = 16; o; o >>= 1) {
            easum += __shfl_xor(easum, o, 32);
            mx = fmaxf(mx, __shfl_xor(mx, o, 32));
        }
        float mean = easum / fmaxf((float)degr, 1.f);
        float lgs = ls[nid * 4 + head] + ldn + mean * wd;
        lgs = lgs > 0.f ? lgs : NEG * lgs;
        mx = fmaxf(mx, lgs);

        float sum = 0.f;
#pragma unroll
        for (int i = 0; i < 4; i++) {
            int e = lane + 32 * i;
            if (e < degr) {
                float p = __expf(lgr[i] - mx);
                albuf[head][e] = p;
                sum += p;
            }
        }
        for (int o = 16; o; o >>= 1) sum += __shfl_xor(sum, o, 32);
        if (lane == 0) {
            float ps = __expf(lgs - mx);
            albuf[head][degr] = ps;
            hsuminv[head] = 1.f / (sum + ps + 1e-16f);
            if (head == 0) srcbuf[degr] = nid << 8;
        }
        __syncthreads();

        int g = t >> 4, l = t & 15;
        int c0 = 8 * l;
        const float* al = albuf[c0 >> 5];
        const char* hb = (const char*)h + 16 * l;
        float acc[8];
#pragma unroll
        for (int j = 0; j < 8; j++) acc[j] = 0.f;
        for (int e0 = g; e0 < deg; e0 += 32) {
            int e1 = e0 + 8, e2 = e0 + 16, e3 = e0 + 24;
            bool v1 = e1 < deg, v2 = e2 < deg, v3 = e3 < deg;
            int i1 = v1 ? e1 : 0, i2 = v2 ? e2 : 0, i3 = v3 ? e3 : 0;
            int o0 = srcbuf[e0], o1 = srcbuf[i1], o2 = srcbuf[i2], o3 = srcbuf[i3];
            int4 r0 = *(const int4*)(hb + o0);
            int4 r1 = *(const int4*)(hb + o1);
            int4 r2 = *(const int4*)(hb + o2);
            int4 r3 = *(const int4*)(hb + o3);
            float a0 = al[e0];
            float a1 = al[i1]; a1 = v1 ? a1 : 0.f;
            float a2 = al[i2]; a2 = v2 ? a2 : 0.f;
            float a3 = al[i3]; a3 = v3 ? a3 : 0.f;
            const __half2* p0 = (const __half2*)&r0;
            const __half2* p1 = (const __half2*)&r1;
            const __half2* p2 = (const __half2*)&r2;
            const __half2* p3 = (const __half2*)&r3;
#pragma unroll
            for (int j = 0; j < 4; j++) {
                float2 f0 = __half22float2(p0[j]);
                float2 f1 = __half22float2(p1[j]);
                float2 f2 = __half22float2(p2[j]);
                float2 f3 = __half22float2(p3[j]);
                acc[2 * j]     = fmaf(a0, f0.x, acc[2 * j]);
                acc[2 * j + 1] = fmaf(a0, f0.y, acc[2 * j + 1]);
                acc[2 * j]     = fmaf(a1, f1.x, acc[2 * j]);
                acc[2 * j + 1] = fmaf(a1, f1.y, acc[2 * j + 1]);
                acc[2 * j]     = fmaf(a2, f2.x, acc[2 * j]);
                acc[2 * j + 1] = fmaf(a2, f2.y, acc[2 * j + 1]);
                acc[2 * j]     = fmaf(a3, f3.x, acc[2 * j]);
                acc[2 * j + 1] = fmaf(a3, f3.y, acc[2 * j + 1]);
            }
        }
#pragma unroll
        for (int j = 0; j < 4; j++)
            *(float2*)&pacc[g][c0 + 2 * j] = make_float2(acc[2 * j], acc[2 * j + 1]);
        __syncthreads();

        float inv = hsuminv[head];
        float sv = pacc[0][t];
#pragma unroll
        for (int g2 = 1; g2 < 8; g2++) sv += pacc[g2][t];
        v = sv * inv + bias[t];
    } else {
        int endr = end - 1;
        float easum = 0.f, mx = -1e30f;
        for (int j = beg + lane; j < endr; j += 32) {
            int2 ce = csr[j];
            float eav = __int_as_float(ce.y);
            easum += eav;
            float lg = ls[ce.x * 4 + head] + ldn + eav * wd;
            lg = lg > 0.f ? lg : NEG * lg;
            mx = fmaxf(mx, lg);
        }
        for (int o = 16; o; o >>= 1) {
            easum += __shfl_xor(easum, o, 32);
            mx = fmaxf(mx, __shfl_xor(mx, o, 32));
        }
        float mean = easum / fmaxf((float)(endr - beg), 1.f);
        float lgs = ls[nid * 4 + head] + ldn + mean * wd;
        lgs = lgs > 0.f ? lgs : NEG * lgs;
        mx = fmaxf(mx, lgs);
        float sum = __expf(lgs - mx);
        float acc = sum * __half2float(h[(size_t)nid * HC + t]);
        for (int j = beg; j < endr; j++) {
            int2 ce = csr[j];
            float lg = ls[ce.x * 4 + head] + ldn + __int_as_float(ce.y) * wd;
            lg = lg > 0.f ? lg : NEG * lg;
            float p = __expf(lg - mx);
            sum += p;
            acc = fmaf(p, __half2float(h[(size_t)ce.x * HC + t]), acc);
        }
        v = acc / (sum + 1e-16f) + bias[t];
        __syncthreads();
        __syncthreads();
    }

    if (RELU) v = fmaxf(v, 0.f);
    if (!FUSE3) out[(size_t)nid * HC + t] = __float2half(v);

    if (FUSE3) {
        float p = v * W3[t];
        for (int o = 32; o; o >>= 1) p += __shfl_xor(p, o, 64);
        __shared__ float sh[2];
        if ((t & 63) == 0) sh[t >> 6] = p;
        __syncthreads();
        if (t == 0) h3[nid] = sh[0] + sh[1];
    }
}

// ---------------- layer 3 (1 head, 1 channel), 8 lanes per node, synth self-loop ----------------
__global__ __launch_bounds__(256) void layer3_k(
        const float* __restrict__ h3, const int* __restrict__ rp,
        const int* __restrict__ boff, const int2* __restrict__ csr,
        const float* __restrict__ wedot, const float* __restrict__ as3,
        const float* __restrict__ ad3, const float* __restrict__ b3,
        float* __restrict__ out, int n) {
    int idx = blockIdx.x * blockDim.x + threadIdx.x;
    int node = idx >> 3, l = idx & 7;
    if (node >= n) return;
    float A = as3[0], D = ad3[0], wd = wedot[8];
    int beg = rp[node] + boff[node >> 8];
    int endr = rp[node + 1] + boff[(node + 1) >> 8] - 1;
    float hs = h3[node];
    float hdn = hs * D;

    float easum = 0.f, mx = -1e30f;
    for (int j = beg + l; j < endr; j += 8) {
        int2 ce = csr[j];
        float eav = __int_as_float(ce.y);
        easum += eav;
        float lg = h3[ce.x] * A + hdn + eav * wd;
        lg = lg > 0.f ? lg : NEG * lg;
        mx = fmaxf(mx, lg);
    }
    easum += __shfl_xor(easum, 1, 8); mx = fmaxf(mx, __shfl_xor(mx, 1, 8));
    easum += __shfl_xor(easum, 2, 8); mx = fmaxf(mx, __shfl_xor(mx, 2, 8));
    easum += __shfl_xor(easum, 4, 8); mx = fmaxf(mx, __shfl_xor(mx, 4, 8));
    float mean = easum / fmaxf((float)(endr - beg), 1.f);
    float lgs = hs * A + hdn + mean * wd;
    lgs = lgs > 0.f ? lgs : NEG * lgs;
    mx = fmaxf(mx, lgs);

    float sum = 0.f, num = 0.f;
    for (int j = beg + l; j < endr; j += 8) {
        int2 ce = csr[j];
        float hv = h3[ce.x];
        float lg = hv * A + hdn + __int_as_float(ce.y) * wd;
        lg = lg > 0.f ? lg : NEG * lg;
        float p = __expf(lg - mx);
        sum += p;
        num = fmaf(p, hv, num);
    }
    sum += __shfl_xor(sum, 1, 8); num += __shfl_xor(num, 1, 8);
    sum += __shfl_xor(sum, 2, 8); num += __shfl_xor(num, 2, 8);
    sum += __shfl_xor(sum, 4, 8); num += __shfl_xor(num, 4, 8);
    if (l == 0) {
        float p = __expf(lgs - mx);
        sum += p;
        num = fmaf(p, hs, num);
        out[node] = num / (sum + 1e-16f) + b3[0];
    }
}

// ---------------- launch ----------------

extern "C" void kernel_launch(void* const* d_in, const int* in_sizes, int n_in,
                              void* d_out, int out_size, void* d_ws, size_t ws_size,
                              hipStream_t stream) {
    const float* x   = (const float*)d_in[0];
    const int*   ei  = (const int*)d_in[1];
    const float* ea  = (const float*)d_in[2];
    const float* W1  = (const float*)d_in[3];
    const float* We1 = (const float*)d_in[4];
    const float* as1 = (const float*)d_in[5];
    const float* ad1 = (const float*)d_in[6];
    const float* ae1 = (const float*)d_in[7];
    const float* b1  = (const float*)d_in[8];
    const float* W2  = (const float*)d_in[9];
    const float* We2 = (const float*)d_in[10];
    const float* as2 = (const float*)d_in[11];
    const float* ad2 = (const float*)d_in[12];
    const float* ae2 = (const float*)d_in[13];
    const float* b2  = (const float*)d_in[14];
    const float* W3  = (const float*)d_in[15];
    const float* We3 = (const float*)d_in[16];
    const float* as3 = (const float*)d_in[17];
    const float* ad3 = (const float*)d_in[18];
    const float* ae3 = (const float*)d_in[19];
    const float* b3  = (const float*)d_in[20];

    const int N = NNODES, E = NEDGES, etot = ETOT;

    char* ws = (char*)d_ws;
    size_t o = 0;
    auto alloc = [&](size_t bytes) { size_t r = o; o = (o + bytes + 255) & ~(size_t)255; return r; };
    size_t o_deg8  = alloc((size_t)NREP * N * 4);
    size_t zero_span = o;                          // memset: deg8 only
    size_t o_off8  = alloc((size_t)NREP * N * 4);
    size_t o_rp    = alloc((size_t)(N + 1) * 4);
    size_t o_bsum  = alloc(256 * 4);
    size_t o_wd    = alloc(16 * 4);
    size_t o_rank  = alloc((size_t)E * 2);
    size_t o_csr   = alloc((size_t)etot * 8);
    size_t o_ls    = alloc((size_t)N * 4 * 4);
    size_t o_ld    = alloc((size_t)N * 4 * 4);
    size_t o_h3    = alloc((size_t)N * 4);
    size_t o_h16   = alloc((size_t)N * HC * 2);
    size_t o_h16b  = alloc((size_t)N * HC * 2);

    int*            deg8  = (int*)(ws + o_deg8);
    int*            off8  = (int*)(ws + o_off8);
    int*            rp    = (int*)(ws + o_rp);
    int*            bsum  = (int*)(ws + o_bsum);
    float*          wd    = (float*)(ws + o_wd);
    unsigned short* rank  = (unsigned short*)(ws + o_rank);
    int2*           csr   = (int2*)(ws + o_csr);
    float*          ls    = (float*)(ws + o_ls);
    float*          ld_   = (float*)(ws + o_ld);
    float*          h3    = (float*)(ws + o_h3);
    __half*         h16   = (__half*)(ws + o_h16);
    __half*         h16b  = (__half*)(ws + o_h16b);

    hipMemsetAsync(ws, 0, zero_span, stream);

    int gB = (N + 63) / 64;          // 782 gemm tiles
    int rB = (E + 255) / 256;        // 6250 rank chunks
    int nb = (N + 255) / 256;

    // fused: gemm layer-1 || edge ranking (replicated) || wedot
    gemm1_rank_fused<<<gB + rB + 1, 256, 0, stream>>>(
        x, W1, as1, ad1, h16, ls, ld_, N,
        ei, rank, deg8, E,
        We1, ae1, We2, ae2, We3, ae3, wd, gB, rB);

    scan_block<<<nb, 256, 0, stream>>>(deg8, off8, rp, bsum, N);
    scan_top<<<1, 256, 0, stream>>>(bsum, nb);
    scatter_k<<<(E + 255) / 256, 256, 0, stream>>>(ei, ea, rp, bsum, off8, rank, csr, E, N);

    // layer 1 aggregation (writes fp16)
    agg_k<true, false><<<N, 128, 0, stream>>>(h16, ls, ld_, rp, bsum, csr, wd, b1,
                                              h16b, nullptr, nullptr, N);
    // layer 2 (+ fused layer-3 projection)
    gemm_lsld<HC, 32, true><<<(N + 31) / 32, 256, 0, stream>>>(h16b, W2, as2, ad2,
                                                               h16, ls, ld_, N);
    agg_k<true, true><<<N, 128, 0, stream>>>(h16, ls, ld_, rp, bsum, csr, wd + 4, b2,
                                             nullptr, W3, h3, N);
    // layer 3
    layer3_k<<<(N * 8 + 255) / 256, 256, 0, stream>>>(h3, rp, bsum, csr, wd, as3, ad3, b3,
                                                      (float*)d_out, N);
}